// Round 1
// baseline (1405.369 us; speedup 1.0000x reference)
//
#include <hip/hip_runtime.h>
#include <cstdint>
#include <cstddef>

// Shapes: B=4, NP=512, PS=16, D=1024, NH=4, HD=256, PH=4, PHD=256, K=5
// Rows of activation matrix: B*NP*PS = 32768. Patches: B*NP = 2048.

typedef __bf16 bf16x8 __attribute__((ext_vector_type(8)));
typedef float floatx4 __attribute__((ext_vector_type(4)));

#define DEV static __device__ __forceinline__

DEV unsigned short f2bf(float f) {
  union { float f; unsigned u; } x; x.f = f;
  unsigned r = x.u + 0x7fffu + ((x.u >> 16) & 1u);  // RNE
  return (unsigned short)(r >> 16);
}
DEV float bf2f(unsigned short b) {
  union { unsigned u; float f; } x; x.u = ((unsigned)b) << 16;
  return x.f;
}
DEV float silu_f(float v) { return v / (1.f + __expf(-v)); }

// block = 256 threads (4 waves); returns full-block sum to all threads
DEV float block_reduce_sum(float v) {
  #pragma unroll
  for (int o = 32; o > 0; o >>= 1) v += __shfl_down(v, o, 64);
  __shared__ float s[4];
  int w = threadIdx.x >> 6;
  if ((threadIdx.x & 63) == 0) s[w] = v;
  __syncthreads();
  return s[0] + s[1] + s[2] + s[3];
}

// ---------------- weight convert fp32 -> bf16 ----------------
__global__ __launch_bounds__(256) void cvt_kernel(const float* __restrict__ in,
                                                  unsigned short* __restrict__ out, int n) {
  int i = (blockIdx.x * 256 + threadIdx.x) * 4;
  if (i < n) {
    float4 v = *(const float4*)(in + i);
    ushort4 o;
    o.x = f2bf(v.x); o.y = f2bf(v.y); o.z = f2bf(v.z); o.w = f2bf(v.w);
    *(ushort4*)(out + i) = o;
  }
}

// ---------------- x = rmsnorm(pbe + local_pos) -> bf16 ----------------
__global__ __launch_bounds__(256) void prep_kernel(const float* __restrict__ pbe,
                                                   const float* __restrict__ pos,
                                                   unsigned short* __restrict__ xn) {
  int row = blockIdx.x;              // 0..32767
  int t = row & 15;                  // position within patch
  const float* ip = pbe + (size_t)row * 1024;
  const float* pp = pos + (size_t)t * 1024;
  int c = threadIdx.x * 4;
  float4 v = *(const float4*)(ip + c);
  float4 p = *(const float4*)(pp + c);
  v.x += p.x; v.y += p.y; v.z += p.z; v.w += p.w;
  float ss = v.x * v.x + v.y * v.y + v.z * v.z + v.w * v.w;
  ss = block_reduce_sum(ss);
  float sc = rsqrtf(ss * (1.f / 1024.f) + 1.1920929e-7f);
  ushort4 o;
  o.x = f2bf(v.x * sc); o.y = f2bf(v.y * sc); o.z = f2bf(v.z * sc); o.w = f2bf(v.w * sc);
  *(ushort4*)(xn + (size_t)row * 1024 + c) = o;
}

// ---------------- generic rmsnorm over D=1024 ----------------
DEV float ldval(const float* p, size_t i) { return p[i]; }
DEV float ldval(const unsigned short* p, size_t i) { return bf2f(p[i]); }
DEV void stval(float* p, size_t i, float v) { p[i] = v; }
DEV void stval(unsigned short* p, size_t i, float v) { p[i] = f2bf(v); }

template <typename TI, typename TO>
__global__ __launch_bounds__(256) void rmsnorm_kernel(const TI* __restrict__ in,
                                                      TO* __restrict__ out) {
  size_t row = blockIdx.x;
  const TI* ip = in + row * 1024;
  TO* op = out + row * 1024;
  int c = threadIdx.x * 4;
  float v[4]; float ss = 0.f;
  #pragma unroll
  for (int j = 0; j < 4; j++) { v[j] = ldval(ip, c + j); ss += v[j] * v[j]; }
  ss = block_reduce_sum(ss);
  float sc = rsqrtf(ss * (1.f / 1024.f) + 1.1920929e-7f);
  #pragma unroll
  for (int j = 0; j < 4; j++) stval(op, c + j, v[j] * sc);
}

// ---------------- GEMM: C[M,N] = A[M,K] @ W[N,K]^T  (bf16 in, fp32 acc) -----
// 128x128 block tile, BK=32, 4 waves in 2x2, each wave 64x64 (4x4 MFMA tiles).
// EPI: 0=store fp32, 1=store bf16, 2=silu->bf16, 3=+res(bf16)->bf16, 4=+res(fp32)->bf16
template <int EPI>
__global__ __launch_bounds__(256) void gemm_bt(
    const unsigned short* __restrict__ A, const unsigned short* __restrict__ Bw,
    int M, int N, int K,
    float* __restrict__ outF, unsigned short* __restrict__ outB,
    const unsigned short* __restrict__ resB, const float* __restrict__ resF) {
  __shared__ __align__(16) unsigned short As[128 * 40];
  __shared__ __align__(16) unsigned short Bs[128 * 40];
  const int tid = threadIdx.x;
  const int bm = blockIdx.x * 128;
  const int bn = blockIdx.y * 128;
  const int wave = tid >> 6, lane = tid & 63;
  const int wy = wave >> 1, wx = wave & 1;
  const int l15 = lane & 15, quad = lane >> 4;

  floatx4 acc[4][4];
  #pragma unroll
  for (int i = 0; i < 4; i++)
    #pragma unroll
    for (int j = 0; j < 4; j++)
      #pragma unroll
      for (int r = 0; r < 4; r++) acc[i][j][r] = 0.f;

  const int srow = tid >> 1;
  const int scol = (tid & 1) * 16;
  const unsigned short* ap = A + (size_t)(bm + srow) * K + scol;
  const unsigned short* bp = Bw + (size_t)(bn + srow) * K + scol;

  for (int k0 = 0; k0 < K; k0 += 32) {
    uint4 av0 = *(const uint4*)(ap + k0);
    uint4 av1 = *(const uint4*)(ap + k0 + 8);
    uint4 bv0 = *(const uint4*)(bp + k0);
    uint4 bv1 = *(const uint4*)(bp + k0 + 8);
    __syncthreads();
    *(uint4*)&As[srow * 40 + scol] = av0;
    *(uint4*)&As[srow * 40 + scol + 8] = av1;
    *(uint4*)&Bs[srow * 40 + scol] = bv0;
    *(uint4*)&Bs[srow * 40 + scol + 8] = bv1;
    __syncthreads();

    bf16x8 afr[4], bfr[4];
    #pragma unroll
    for (int i = 0; i < 4; i++)
      afr[i] = *(const bf16x8*)&As[(wy * 64 + i * 16 + l15) * 40 + quad * 8];
    #pragma unroll
    for (int j = 0; j < 4; j++)
      bfr[j] = *(const bf16x8*)&Bs[(wx * 64 + j * 16 + l15) * 40 + quad * 8];
    #pragma unroll
    for (int i = 0; i < 4; i++)
      #pragma unroll
      for (int j = 0; j < 4; j++)
        acc[i][j] = __builtin_amdgcn_mfma_f32_16x16x32_bf16(afr[i], bfr[j], acc[i][j], 0, 0, 0);
  }

  #pragma unroll
  for (int i = 0; i < 4; i++)
    #pragma unroll
    for (int j = 0; j < 4; j++) {
      int gm = bm + wy * 64 + i * 16 + quad * 4;
      int gn = bn + wx * 64 + j * 16 + l15;
      #pragma unroll
      for (int r = 0; r < 4; r++) {
        float v = acc[i][j][r];
        size_t idx = (size_t)(gm + r) * N + gn;
        if (EPI == 0) outF[idx] = v;
        else if (EPI == 1) outB[idx] = f2bf(v);
        else if (EPI == 2) outB[idx] = f2bf(silu_f(v));
        else if (EPI == 3) outB[idx] = f2bf(v + bf2f(resB[idx]));
        else if (EPI == 4) outB[idx] = f2bf(v + resF[idx]);
      }
    }
}

// ---------------- fused dual GEMM: h = silu(A@Wg^T) * (A@Wi^T) -> bf16 ------
__global__ __launch_bounds__(256) void gemm_dual(
    const unsigned short* __restrict__ A, const unsigned short* __restrict__ Bg,
    const unsigned short* __restrict__ Bi, int M, int N, int K,
    unsigned short* __restrict__ outH) {
  __shared__ __align__(16) unsigned short As[128 * 40];
  __shared__ __align__(16) unsigned short Gs[128 * 40];
  __shared__ __align__(16) unsigned short Is[128 * 40];
  const int tid = threadIdx.x;
  const int bm = blockIdx.x * 128;
  const int bn = blockIdx.y * 128;
  const int wave = tid >> 6, lane = tid & 63;
  const int wy = wave >> 1, wx = wave & 1;
  const int l15 = lane & 15, quad = lane >> 4;

  floatx4 accg[4][4], acci[4][4];
  #pragma unroll
  for (int i = 0; i < 4; i++)
    #pragma unroll
    for (int j = 0; j < 4; j++)
      #pragma unroll
      for (int r = 0; r < 4; r++) { accg[i][j][r] = 0.f; acci[i][j][r] = 0.f; }

  const int srow = tid >> 1;
  const int scol = (tid & 1) * 16;
  const unsigned short* ap = A + (size_t)(bm + srow) * K + scol;
  const unsigned short* gp = Bg + (size_t)(bn + srow) * K + scol;
  const unsigned short* ipp = Bi + (size_t)(bn + srow) * K + scol;

  for (int k0 = 0; k0 < K; k0 += 32) {
    uint4 av0 = *(const uint4*)(ap + k0);
    uint4 av1 = *(const uint4*)(ap + k0 + 8);
    uint4 gv0 = *(const uint4*)(gp + k0);
    uint4 gv1 = *(const uint4*)(gp + k0 + 8);
    uint4 iv0 = *(const uint4*)(ipp + k0);
    uint4 iv1 = *(const uint4*)(ipp + k0 + 8);
    __syncthreads();
    *(uint4*)&As[srow * 40 + scol] = av0;
    *(uint4*)&As[srow * 40 + scol + 8] = av1;
    *(uint4*)&Gs[srow * 40 + scol] = gv0;
    *(uint4*)&Gs[srow * 40 + scol + 8] = gv1;
    *(uint4*)&Is[srow * 40 + scol] = iv0;
    *(uint4*)&Is[srow * 40 + scol + 8] = iv1;
    __syncthreads();

    bf16x8 afr[4], gfr[4], ifr[4];
    #pragma unroll
    for (int i = 0; i < 4; i++)
      afr[i] = *(const bf16x8*)&As[(wy * 64 + i * 16 + l15) * 40 + quad * 8];
    #pragma unroll
    for (int j = 0; j < 4; j++) {
      gfr[j] = *(const bf16x8*)&Gs[(wx * 64 + j * 16 + l15) * 40 + quad * 8];
      ifr[j] = *(const bf16x8*)&Is[(wx * 64 + j * 16 + l15) * 40 + quad * 8];
    }
    #pragma unroll
    for (int i = 0; i < 4; i++)
      #pragma unroll
      for (int j = 0; j < 4; j++) {
        accg[i][j] = __builtin_amdgcn_mfma_f32_16x16x32_bf16(afr[i], gfr[j], accg[i][j], 0, 0, 0);
        acci[i][j] = __builtin_amdgcn_mfma_f32_16x16x32_bf16(afr[i], ifr[j], acci[i][j], 0, 0, 0);
      }
  }

  #pragma unroll
  for (int i = 0; i < 4; i++)
    #pragma unroll
    for (int j = 0; j < 4; j++) {
      int gm = bm + wy * 64 + i * 16 + quad * 4;
      int gn = bn + wx * 64 + j * 16 + l15;
      #pragma unroll
      for (int r = 0; r < 4; r++) {
        size_t idx = (size_t)(gm + r) * N + gn;
        outH[idx] = f2bf(silu_f(accg[i][j][r]) * acci[i][j][r]);
      }
    }
}

// ---------------- depthwise causal conv (K=5) + residual ----------------
__global__ __launch_bounds__(256) void conv_kernel(const unsigned short* __restrict__ h,
                                                   const float* __restrict__ cw,
                                                   unsigned short* __restrict__ x2) {
  int patch = blockIdx.x;  // 0..2047
  __shared__ __align__(16) unsigned short hs[16 * 1024];
  const int tid = threadIdx.x;
  size_t base = (size_t)patch * 16384;
  for (int idx = tid * 8; idx < 16384; idx += 256 * 8)
    *(uint4*)&hs[idx] = *(const uint4*)&h[base + idx];
  __syncthreads();
  for (int idx = tid; idx < 16384; idx += 256) {
    int t = idx >> 10, c = idx & 1023;
    float acc = bf2f(hs[idx]);  // residual
    #pragma unroll
    for (int k = 0; k < 5; k++) {
      int tt = t + k - 4;
      if (tt >= 0) acc += cw[c * 5 + k] * bf2f(hs[tt * 1024 + c]);
    }
    x2[base + idx] = f2bf(acc);
  }
}

// ---------------- per-patch per-head attention (PS=16, HD=256) ----------------
__global__ __launch_bounds__(256) void attn_kernel(const unsigned short* __restrict__ qkv,
                                                   unsigned short* __restrict__ sa) {
  int patch = blockIdx.x;  // 0..2047
  int head = blockIdx.y;   // 0..3
  const int tid = threadIdx.x;
  __shared__ float qs[16][257], ks[16][257], vs[16][257];
  __shared__ float sc[16][16];
  size_t base = (size_t)patch * 16 * 3072 + (size_t)head * 256;
  for (int idx = tid; idx < 16 * 256; idx += 256) {
    int t = idx >> 8, d = idx & 255;
    size_t roff = base + (size_t)t * 3072 + d;
    qs[t][d] = bf2f(qkv[roff]);
    ks[t][d] = bf2f(qkv[roff + 1024]);
    vs[t][d] = bf2f(qkv[roff + 2048]);
  }
  __syncthreads();
  {  // scores: one (t,kk) per thread
    int t = tid >> 4, kk = tid & 15;
    float s = 0.f;
    for (int d = 0; d < 256; d++) s += qs[t][d] * ks[kk][d];
    sc[t][kk] = s * 0.0625f;  // HD^-0.5
  }
  __syncthreads();
  if (tid < 16) {  // softmax over kk per row t
    float m = -1e30f;
    for (int kk = 0; kk < 16; kk++) m = fmaxf(m, sc[tid][kk]);
    float p[16], sum = 0.f;
    for (int kk = 0; kk < 16; kk++) { p[kk] = __expf(sc[tid][kk] - m); sum += p[kk]; }
    float inv = 1.f / sum;
    for (int kk = 0; kk < 16; kk++) sc[tid][kk] = p[kk] * inv;
  }
  __syncthreads();
  for (int idx = tid; idx < 4096; idx += 256) {
    int t = idx >> 8, d = idx & 255;
    float o = 0.f;
    #pragma unroll
    for (int kk = 0; kk < 16; kk++) o += sc[t][kk] * vs[kk][d];
    sa[(size_t)(patch * 16 + t) * 1024 + head * 256 + d] = f2bf(o);
  }
}

// ---------------- head pooling: logits -> softmax over t -> weighted sum -----
__global__ __launch_bounds__(256) void pool_kernel(const unsigned short* __restrict__ x4,
                                                   const float* __restrict__ wpool,
                                                   const float* __restrict__ tptr,
                                                   float* __restrict__ pooled) {
  int patch = blockIdx.x;  // 0..2047
  __shared__ __align__(16) unsigned short xs[16 * 1024];
  __shared__ float lg[4][16], aw[4][16];
  const int tid = threadIdx.x;
  size_t base = (size_t)patch * 16384;
  for (int idx = tid * 8; idx < 16384; idx += 256 * 8)
    *(uint4*)&xs[idx] = *(const uint4*)&x4[base + idx];
  __syncthreads();
  {  // 64 (t,h) pairs x 4 threads each over 256 dims
    int pair = tid >> 2, sub = tid & 3;
    int t = pair >> 2, hh = pair & 3;
    float s = 0.f;
    for (int d = sub * 256; d < sub * 256 + 256; d++)
      s += bf2f(xs[t * 1024 + d]) * wpool[hh * 1024 + d];
    s += __shfl_down(s, 2, 64);
    s += __shfl_down(s, 1, 64);
    if (sub == 0) {
      float temp = fmaxf(tptr[0], 0.01f);
      lg[hh][t] = s / temp;
    }
  }
  __syncthreads();
  if (tid < 4) {  // softmax over t
    int hh = tid;
    float m = -1e30f;
    for (int t = 0; t < 16; t++) m = fmaxf(m, lg[hh][t]);
    float p[16], sum = 0.f;
    for (int t = 0; t < 16; t++) { p[t] = __expf(lg[hh][t] - m); sum += p[t]; }
    float inv = 1.f / sum;
    for (int t = 0; t < 16; t++) aw[hh][t] = p[t] * inv;
  }
  __syncthreads();
  for (int c = tid; c < 1024; c += 256) {
    int hh = c >> 8;
    float o = 0.f;
    #pragma unroll
    for (int t = 0; t < 16; t++) o += aw[hh][t] * bf2f(xs[t * 1024 + c]);
    pooled[(size_t)patch * 1024 + c] = o;
  }
}

extern "C" void kernel_launch(void* const* d_in, const int* in_sizes, int n_in,
                              void* d_out, int out_size, void* d_ws, size_t ws_size,
                              hipStream_t stream) {
  (void)in_sizes; (void)n_in; (void)out_size; (void)ws_size;
  const float* pbe  = (const float*)d_in[0];   // (4,512,16,1024)
  const float* lpos = (const float*)d_in[1];   // (16,1024)
  const float* wg   = (const float*)d_in[2];
  const float* wi   = (const float*)d_in[3];
  const float* cw   = (const float*)d_in[4];   // (1024,1,5)
  const float* wqkv = (const float*)d_in[5];   // (3072,1024)
  const float* wio  = (const float*)d_in[6];
  const float* wpl  = (const float*)d_in[7];   // (4,1024)
  const float* temp = (const float*)d_in[8];
  const float* wup  = (const float*)d_in[9];
  const float* wdn  = (const float*)d_in[10];
  const float* wout = (const float*)d_in[11];
  float* outp = (float*)d_out;                 // (4,512,1024) fp32

  const int ROWS = 32768, Dm = 1024, NPAT = 2048;

  char* p = (char*)d_ws;
  auto take = [&](size_t nbytes) { void* r = (void*)p; p += (nbytes + 255) & ~(size_t)255; return r; };
  unsigned short* wg_b   = (unsigned short*)take((size_t)Dm * Dm * 2);
  unsigned short* wi_b   = (unsigned short*)take((size_t)Dm * Dm * 2);
  unsigned short* wqkv_b = (unsigned short*)take((size_t)3 * Dm * Dm * 2);
  unsigned short* wio_b  = (unsigned short*)take((size_t)Dm * Dm * 2);
  unsigned short* wup_b  = (unsigned short*)take((size_t)Dm * Dm * 2);
  unsigned short* wdn_b  = (unsigned short*)take((size_t)Dm * Dm * 2);
  unsigned short* wout_b = (unsigned short*)take((size_t)Dm * Dm * 2);
  unsigned short* slotA  = (unsigned short*)take((size_t)ROWS * Dm * 2);  // xn / x2n / x4
  unsigned short* slotB  = (unsigned short*)take((size_t)ROWS * Dm * 2);  // h / sa
  unsigned short* slotC  = (unsigned short*)take((size_t)ROWS * Dm * 2);  // x2 / x3
  unsigned short* qkvB   = (unsigned short*)take((size_t)ROWS * 3 * Dm * 2);
  float*          pooled = (float*)take((size_t)NPAT * Dm * 4);
  unsigned short* pooledn= (unsigned short*)take((size_t)NPAT * Dm * 2);
  unsigned short* ubuf   = (unsigned short*)take((size_t)NPAT * Dm * 2);
  unsigned short* y1b    = (unsigned short*)take((size_t)NPAT * Dm * 2);
  float*          y2     = (float*)take((size_t)NPAT * Dm * 4);

  auto cvt = [&](const float* src, unsigned short* dst, int n) {
    cvt_kernel<<<dim3((n / 4 + 255) / 256), dim3(256), 0, stream>>>(src, dst, n);
  };
  cvt(wg, wg_b, Dm * Dm);
  cvt(wi, wi_b, Dm * Dm);
  cvt(wqkv, wqkv_b, 3 * Dm * Dm);
  cvt(wio, wio_b, Dm * Dm);
  cvt(wup, wup_b, Dm * Dm);
  cvt(wdn, wdn_b, Dm * Dm);
  cvt(wout, wout_b, Dm * Dm);

  // 1. xn = rmsnorm(pbe + pos)
  prep_kernel<<<dim3(ROWS), dim3(256), 0, stream>>>(pbe, lpos, slotA);
  // 2. h = silu(xn@wg^T) * (xn@wi^T)
  gemm_dual<<<dim3(ROWS / 128, Dm / 128), dim3(256), 0, stream>>>(
      slotA, wg_b, wi_b, ROWS, Dm, Dm, slotB);
  // 3. x2 = h + depthwise_causal_conv(h)
  conv_kernel<<<dim3(NPAT), dim3(256), 0, stream>>>(slotB, cw, slotC);
  // 4. x2n = rmsnorm(x2)
  rmsnorm_kernel<unsigned short, unsigned short><<<dim3(ROWS), dim3(256), 0, stream>>>(slotC, slotA);
  // 5. qkv = x2n @ wqkv^T
  gemm_bt<1><<<dim3(ROWS / 128, 3 * Dm / 128), dim3(256), 0, stream>>>(
      slotA, wqkv_b, ROWS, 3 * Dm, Dm, nullptr, qkvB, nullptr, nullptr);
  // 6. sa = attention(qkv)
  attn_kernel<<<dim3(NPAT, 4), dim3(256), 0, stream>>>(qkvB, slotB);
  // 7. x3 = x2 + sa @ wio^T   (in-place into slotC)
  gemm_bt<3><<<dim3(ROWS / 128, Dm / 128), dim3(256), 0, stream>>>(
      slotB, wio_b, ROWS, Dm, Dm, nullptr, slotC, slotC, nullptr);
  // 8. x4 = rmsnorm(x3)
  rmsnorm_kernel<unsigned short, unsigned short><<<dim3(ROWS), dim3(256), 0, stream>>>(slotC, slotA);
  // 9. pooled = headwise softmax-pool(x4)
  pool_kernel<<<dim3(NPAT), dim3(256), 0, stream>>>(slotA, wpl, temp, pooled);
  // 10. pooledn = rmsnorm(pooled)
  rmsnorm_kernel<float, unsigned short><<<dim3(NPAT), dim3(256), 0, stream>>>(pooled, pooledn);
  // 11. u = silu(pooledn @ wup^T)
  gemm_bt<2><<<dim3(NPAT / 128, Dm / 128), dim3(256), 0, stream>>>(
      pooledn, wup_b, NPAT, Dm, Dm, nullptr, ubuf, nullptr, nullptr);
  // 12. y1 = pooled + u @ wdn^T
  gemm_bt<4><<<dim3(NPAT / 128, Dm / 128), dim3(256), 0, stream>>>(
      ubuf, wdn_b, NPAT, Dm, Dm, nullptr, y1b, nullptr, pooled);
  // 13. y2 = y1 @ wout^T
  gemm_bt<0><<<dim3(NPAT / 128, Dm / 128), dim3(256), 0, stream>>>(
      y1b, wout_b, NPAT, Dm, Dm, y2, nullptr, nullptr, nullptr);
  // 14. out = rmsnorm(y2)
  rmsnorm_kernel<float, float><<<dim3(NPAT), dim3(256), 0, stream>>>(y2, outp);
}

// Round 2
// 1395.196 us; speedup vs baseline: 1.0073x; 1.0073x over previous
//
#include <hip/hip_runtime.h>
#include <cstdint>
#include <cstddef>

// Shapes: B=4, NP=512, PS=16, D=1024, NH=4, HD=256, PH=4, PHD=256, K=5
// Rows of activation matrix: B*NP*PS = 32768. Patches: B*NP = 2048.

typedef __bf16 bf16x8 __attribute__((ext_vector_type(8)));
typedef float floatx4 __attribute__((ext_vector_type(4)));

#define DEV static __device__ __forceinline__

DEV unsigned short f2bf(float f) {
  union { float f; unsigned u; } x; x.f = f;
  unsigned r = x.u + 0x7fffu + ((x.u >> 16) & 1u);  // RNE
  return (unsigned short)(r >> 16);
}
DEV float bf2f(unsigned short b) {
  union { unsigned u; float f; } x; x.u = ((unsigned)b) << 16;
  return x.f;
}
DEV float silu_f(float v) { return v / (1.f + __expf(-v)); }

// async global->LDS, 16 bytes per lane. LDS dest is wave-uniform base + lane*16.
DEV void gl_lds16(const unsigned short* g, unsigned short* l) {
  __builtin_amdgcn_global_load_lds(
      (const __attribute__((address_space(1))) void*)g,
      (__attribute__((address_space(3))) void*)l, 16, 0, 0);
}

// block = 256 threads (4 waves); returns full-block sum to all threads
DEV float block_reduce_sum(float v) {
  #pragma unroll
  for (int o = 32; o > 0; o >>= 1) v += __shfl_down(v, o, 64);
  __shared__ float s[4];
  int w = threadIdx.x >> 6;
  if ((threadIdx.x & 63) == 0) s[w] = v;
  __syncthreads();
  return s[0] + s[1] + s[2] + s[3];
}

// ---------------- weight convert fp32 -> bf16 (all weights, one launch) -----
struct CvtArgs {
  const float* src[7];
  unsigned short* dst[7];
  int blkoff[8];  // block ranges per weight (1024 elems per block)
};
__global__ __launch_bounds__(256) void cvt_all(CvtArgs a) {
  int b = blockIdx.x;
  int w = 0;
  #pragma unroll
  for (int i = 0; i < 6; i++) w += (b >= a.blkoff[i + 1]) ? 1 : 0;
  int i = (b - a.blkoff[w]) * 1024 + threadIdx.x * 4;
  float4 v = *(const float4*)(a.src[w] + i);
  ushort4 o;
  o.x = f2bf(v.x); o.y = f2bf(v.y); o.z = f2bf(v.z); o.w = f2bf(v.w);
  *(ushort4*)(a.dst[w] + i) = o;
}

// ---------------- x = rmsnorm(pbe + local_pos) -> bf16 ----------------
__global__ __launch_bounds__(256) void prep_kernel(const float* __restrict__ pbe,
                                                   const float* __restrict__ pos,
                                                   unsigned short* __restrict__ xn) {
  int row = blockIdx.x;              // 0..32767
  int t = row & 15;                  // position within patch
  const float* ip = pbe + (size_t)row * 1024;
  const float* pp = pos + (size_t)t * 1024;
  int c = threadIdx.x * 4;
  float4 v = *(const float4*)(ip + c);
  float4 p = *(const float4*)(pp + c);
  v.x += p.x; v.y += p.y; v.z += p.z; v.w += p.w;
  float ss = v.x * v.x + v.y * v.y + v.z * v.z + v.w * v.w;
  ss = block_reduce_sum(ss);
  float sc = rsqrtf(ss * (1.f / 1024.f) + 1.1920929e-7f);
  ushort4 o;
  o.x = f2bf(v.x * sc); o.y = f2bf(v.y * sc); o.z = f2bf(v.z * sc); o.w = f2bf(v.w * sc);
  *(ushort4*)(xn + (size_t)row * 1024 + c) = o;
}

// ---------------- generic rmsnorm over D=1024 ----------------
DEV float ldval(const float* p, size_t i) { return p[i]; }
DEV float ldval(const unsigned short* p, size_t i) { return bf2f(p[i]); }
DEV void stval(float* p, size_t i, float v) { p[i] = v; }
DEV void stval(unsigned short* p, size_t i, float v) { p[i] = f2bf(v); }

template <typename TI, typename TO>
__global__ __launch_bounds__(256) void rmsnorm_kernel(const TI* __restrict__ in,
                                                      TO* __restrict__ out) {
  size_t row = blockIdx.x;
  const TI* ip = in + row * 1024;
  TO* op = out + row * 1024;
  int c = threadIdx.x * 4;
  float v[4]; float ss = 0.f;
  #pragma unroll
  for (int j = 0; j < 4; j++) { v[j] = ldval(ip, c + j); ss += v[j] * v[j]; }
  ss = block_reduce_sum(ss);
  float sc = rsqrtf(ss * (1.f / 1024.f) + 1.1920929e-7f);
  #pragma unroll
  for (int j = 0; j < 4; j++) stval(op, c + j, v[j] * sc);
}

// ============ GEMM core: m97-style global_load_lds staging ============
// Tile 128x128, BK=32. LDS tile: 128 rows x 32 elems (64 B/row), unpadded.
// XOR swizzle on the GLOBAL side: lane (i%4) loads chunk (i%4)^((row>>1)&3),
// so fragment reads at chunk q^((row>>1)&3) hit each bank-quad exactly 2-way
// (free per m136). Staging writes are lane-contiguous (conflict-free DMA).

// stage one 128x32 tile: wave issues 2x 1KiB instructions
DEV void stage_tile(const unsigned short* __restrict__ src, size_t ld,
                    unsigned short* lds, int wave, int lane, int k0) {
  int r0 = wave * 32 + (lane >> 2);
  int r1 = r0 + 16;
  int c0 = (lane & 3) ^ ((r0 >> 1) & 3);
  int c1 = (lane & 3) ^ ((r1 >> 1) & 3);
  gl_lds16(src + (size_t)r0 * ld + k0 + c0 * 8, lds + wave * 1024);
  gl_lds16(src + (size_t)r1 * ld + k0 + c1 * 8, lds + wave * 1024 + 512);
}
// LDS elem offset of fragment (row, quad)
DEV int frag_off(int row, int quad) {
  return row * 32 + ((quad ^ ((row >> 1) & 3)) * 8);
}

// C[M,N] = A[M,K] @ W[N,K]^T (bf16 in, fp32 acc)
// EPI: 0=store fp32, 1=store bf16, 2=silu->bf16, 3=+res(bf16)->bf16, 4=+res(fp32)->bf16
template <int EPI>
__global__ __launch_bounds__(256) void gemm_bt(
    const unsigned short* __restrict__ A, const unsigned short* __restrict__ Bw,
    int M, int N, int K,
    float* __restrict__ outF, unsigned short* __restrict__ outB,
    const unsigned short* __restrict__ resB, const float* __restrict__ resF) {
  __shared__ __align__(16) unsigned short As[128 * 32];
  __shared__ __align__(16) unsigned short Bs[128 * 32];
  const int tid = threadIdx.x;
  const int bm = blockIdx.x * 128, bn = blockIdx.y * 128;
  const int wave = tid >> 6, lane = tid & 63;
  const int wy = wave >> 1, wx = wave & 1;
  const int l15 = lane & 15, quad = lane >> 4;

  floatx4 acc[4][4];
  #pragma unroll
  for (int i = 0; i < 4; i++)
    #pragma unroll
    for (int j = 0; j < 4; j++)
      #pragma unroll
      for (int r = 0; r < 4; r++) acc[i][j][r] = 0.f;

  const unsigned short* Ab = A + (size_t)bm * K;
  const unsigned short* Bb = Bw + (size_t)bn * K;
  int aoff[4], boff[4];
  #pragma unroll
  for (int i = 0; i < 4; i++) {
    aoff[i] = frag_off(wy * 64 + i * 16 + l15, quad);
    boff[i] = frag_off(wx * 64 + i * 16 + l15, quad);
  }

  for (int k0 = 0; k0 < K; k0 += 32) {
    __syncthreads();                       // previous tile's reads done
    stage_tile(Ab, K, As, wave, lane, k0);
    stage_tile(Bb, K, Bs, wave, lane, k0);
    __syncthreads();                       // staging complete (vmcnt drained)
    bf16x8 afr[4], bfr[4];
    #pragma unroll
    for (int i = 0; i < 4; i++) afr[i] = *(const bf16x8*)&As[aoff[i]];
    #pragma unroll
    for (int j = 0; j < 4; j++) bfr[j] = *(const bf16x8*)&Bs[boff[j]];
    #pragma unroll
    for (int i = 0; i < 4; i++)
      #pragma unroll
      for (int j = 0; j < 4; j++)
        acc[i][j] = __builtin_amdgcn_mfma_f32_16x16x32_bf16(afr[i], bfr[j], acc[i][j], 0, 0, 0);
  }

  #pragma unroll
  for (int i = 0; i < 4; i++)
    #pragma unroll
    for (int j = 0; j < 4; j++) {
      int gm = bm + wy * 64 + i * 16 + quad * 4;
      int gn = bn + wx * 64 + j * 16 + l15;
      #pragma unroll
      for (int r = 0; r < 4; r++) {
        float v = acc[i][j][r];
        size_t idx = (size_t)(gm + r) * N + gn;
        if (EPI == 0) outF[idx] = v;
        else if (EPI == 1) outB[idx] = f2bf(v);
        else if (EPI == 2) outB[idx] = f2bf(silu_f(v));
        else if (EPI == 3) outB[idx] = f2bf(v + bf2f(resB[idx]));
        else if (EPI == 4) outB[idx] = f2bf(v + resF[idx]);
      }
    }
}

// ---------------- fused dual GEMM: h = silu(A@Wg^T) * (A@Wi^T) -> bf16 ------
__global__ __launch_bounds__(256) void gemm_dual(
    const unsigned short* __restrict__ A, const unsigned short* __restrict__ Bg,
    const unsigned short* __restrict__ Bi, int M, int N, int K,
    unsigned short* __restrict__ outH) {
  __shared__ __align__(16) unsigned short As[128 * 32];
  __shared__ __align__(16) unsigned short Gs[128 * 32];
  __shared__ __align__(16) unsigned short Is[128 * 32];
  const int tid = threadIdx.x;
  const int bm = blockIdx.x * 128, bn = blockIdx.y * 128;
  const int wave = tid >> 6, lane = tid & 63;
  const int wy = wave >> 1, wx = wave & 1;
  const int l15 = lane & 15, quad = lane >> 4;

  floatx4 accg[4][4], acci[4][4];
  #pragma unroll
  for (int i = 0; i < 4; i++)
    #pragma unroll
    for (int j = 0; j < 4; j++)
      #pragma unroll
      for (int r = 0; r < 4; r++) { accg[i][j][r] = 0.f; acci[i][j][r] = 0.f; }

  const unsigned short* Ab = A + (size_t)bm * K;
  const unsigned short* Gb = Bg + (size_t)bn * K;
  const unsigned short* Ib = Bi + (size_t)bn * K;
  int aoff[4], boff[4];
  #pragma unroll
  for (int i = 0; i < 4; i++) {
    aoff[i] = frag_off(wy * 64 + i * 16 + l15, quad);
    boff[i] = frag_off(wx * 64 + i * 16 + l15, quad);
  }

  for (int k0 = 0; k0 < K; k0 += 32) {
    __syncthreads();
    stage_tile(Ab, K, As, wave, lane, k0);
    stage_tile(Gb, K, Gs, wave, lane, k0);
    stage_tile(Ib, K, Is, wave, lane, k0);
    __syncthreads();
    bf16x8 afr[4], gfr[4], ifr[4];
    #pragma unroll
    for (int i = 0; i < 4; i++) afr[i] = *(const bf16x8*)&As[aoff[i]];
    #pragma unroll
    for (int j = 0; j < 4; j++) {
      gfr[j] = *(const bf16x8*)&Gs[boff[j]];
      ifr[j] = *(const bf16x8*)&Is[boff[j]];
    }
    #pragma unroll
    for (int i = 0; i < 4; i++)
      #pragma unroll
      for (int j = 0; j < 4; j++) {
        accg[i][j] = __builtin_amdgcn_mfma_f32_16x16x32_bf16(afr[i], gfr[j], accg[i][j], 0, 0, 0);
        acci[i][j] = __builtin_amdgcn_mfma_f32_16x16x32_bf16(afr[i], ifr[j], acci[i][j], 0, 0, 0);
      }
  }

  #pragma unroll
  for (int i = 0; i < 4; i++)
    #pragma unroll
    for (int j = 0; j < 4; j++) {
      int gm = bm + wy * 64 + i * 16 + quad * 4;
      int gn = bn + wx * 64 + j * 16 + l15;
      #pragma unroll
      for (int r = 0; r < 4; r++) {
        size_t idx = (size_t)(gm + r) * N + gn;
        outH[idx] = f2bf(silu_f(accg[i][j][r]) * acci[i][j][r]);
      }
    }
}

// ------- fused depthwise causal conv (K=5) + residual + rmsnorm -------
// outputs x2 = h + conv(h) and x2n = rmsnorm(x2)
__global__ __launch_bounds__(256) void conv_rms_kernel(const unsigned short* __restrict__ h,
                                                       const float* __restrict__ cw,
                                                       unsigned short* __restrict__ x2,
                                                       unsigned short* __restrict__ x2n) {
  int patch = blockIdx.x;  // 0..2047
  __shared__ __align__(16) unsigned short hs[16 * 1024];
  __shared__ __align__(16) float cws[5120];
  const int tid = threadIdx.x;
  size_t base = (size_t)patch * 16384;
  for (int idx = tid * 8; idx < 16384; idx += 256 * 8)
    *(uint4*)&hs[idx] = *(const uint4*)&h[base + idx];
  for (int i = tid * 4; i < 5120; i += 256 * 4)
    *(float4*)&cws[i] = *(const float4*)&cw[i];
  __syncthreads();
  // thread handles row t = tid>>4, cols (tid&15)*8 + jb*128 + i  (i<8, jb<8)
  int t = tid >> 4;
  int lc = (tid & 15) * 8;
  float vals[8][8];
  float ss = 0.f;
  #pragma unroll
  for (int jb = 0; jb < 8; jb++) {
    #pragma unroll
    for (int i = 0; i < 8; i++) {
      int c = jb * 128 + lc + i;
      float acc = bf2f(hs[t * 1024 + c]);  // residual
      #pragma unroll
      for (int k = 0; k < 5; k++) {
        int tt = t + k - 4;
        if (tt >= 0) acc += cws[c * 5 + k] * bf2f(hs[tt * 1024 + c]);
      }
      vals[jb][i] = acc;
      ss += acc * acc;
    }
  }
  // reduce over the 16 lanes sharing row t
  ss += __shfl_down(ss, 8, 16);
  ss += __shfl_down(ss, 4, 16);
  ss += __shfl_down(ss, 2, 16);
  ss += __shfl_down(ss, 1, 16);
  ss = __shfl(ss, 0, 16);
  float sc = rsqrtf(ss * (1.f / 1024.f) + 1.1920929e-7f);
  #pragma unroll
  for (int jb = 0; jb < 8; jb++) {
    ushort4 o2[2], on[2];
    #pragma unroll
    for (int i = 0; i < 8; i++) {
      ((unsigned short*)o2)[i] = f2bf(vals[jb][i]);
      ((unsigned short*)on)[i] = f2bf(vals[jb][i] * sc);
    }
    size_t off = base + (size_t)t * 1024 + jb * 128 + lc;
    *(uint4*)&x2[off] = *(uint4*)o2;
    *(uint4*)&x2n[off] = *(uint4*)on;
  }
}

// ---------------- per-patch per-head attention (PS=16, HD=256) ----------------
__global__ __launch_bounds__(256) void attn_kernel(const unsigned short* __restrict__ qkv,
                                                   unsigned short* __restrict__ sa) {
  int patch = blockIdx.x;  // 0..2047
  int head = blockIdx.y;   // 0..3
  const int tid = threadIdx.x;
  __shared__ float qs[16][260], ks[16][260], vs[16][260];
  __shared__ float sc[16][16];
  size_t base = (size_t)patch * 16 * 3072 + (size_t)head * 256;
  for (int idx = tid * 8; idx < 16 * 256; idx += 256 * 8) {
    int t = idx >> 8, d = idx & 255;
    size_t roff = base + (size_t)t * 3072 + d;
    uint4 qv = *(const uint4*)&qkv[roff];
    uint4 kv = *(const uint4*)&qkv[roff + 1024];
    uint4 vv = *(const uint4*)&qkv[roff + 2048];
    const unsigned short* qp = (const unsigned short*)&qv;
    const unsigned short* kp = (const unsigned short*)&kv;
    const unsigned short* vp = (const unsigned short*)&vv;
    #pragma unroll
    for (int i = 0; i < 8; i++) {
      qs[t][d + i] = bf2f(qp[i]);
      ks[t][d + i] = bf2f(kp[i]);
      vs[t][d + i] = bf2f(vp[i]);
    }
  }
  __syncthreads();
  {  // scores: one (t,kk) per thread
    int t = tid >> 4, kk = tid & 15;
    float s = 0.f;
    for (int d = 0; d < 256; d++) s += qs[t][d] * ks[kk][d];
    sc[t][kk] = s * 0.0625f;  // HD^-0.5
  }
  __syncthreads();
  if (tid < 16) {  // softmax over kk per row t
    float m = -1e30f;
    for (int kk = 0; kk < 16; kk++) m = fmaxf(m, sc[tid][kk]);
    float p[16], sum = 0.f;
    for (int kk = 0; kk < 16; kk++) { p[kk] = __expf(sc[tid][kk] - m); sum += p[kk]; }
    float inv = 1.f / sum;
    for (int kk = 0; kk < 16; kk++) sc[tid][kk] = p[kk] * inv;
  }
  __syncthreads();
  for (int idx = tid * 8; idx < 4096; idx += 256 * 8) {
    int t = idx >> 8, d = idx & 255;
    ushort4 o[2];
    #pragma unroll
    for (int i = 0; i < 8; i++) {
      float v = 0.f;
      #pragma unroll
      for (int kk = 0; kk < 16; kk++) v += sc[t][kk] * vs[kk][d + i];
      ((unsigned short*)o)[i] = f2bf(v);
    }
    *(uint4*)&sa[(size_t)(patch * 16 + t) * 1024 + head * 256 + d] = *(uint4*)o;
  }
}

// ---------------- head pooling: logits -> softmax over t -> weighted sum -----
__global__ __launch_bounds__(256) void pool_kernel(const unsigned short* __restrict__ x4,
                                                   const float* __restrict__ wpool,
                                                   const float* __restrict__ tptr,
                                                   float* __restrict__ pooled) {
  int patch = blockIdx.x;  // 0..2047
  __shared__ __align__(16) unsigned short xs[16 * 1024];
  __shared__ float lg[4][16], aw[4][16];
  const int tid = threadIdx.x;
  size_t base = (size_t)patch * 16384;
  for (int idx = tid * 8; idx < 16384; idx += 256 * 8)
    *(uint4*)&xs[idx] = *(const uint4*)&x4[base + idx];
  __syncthreads();
  {  // 64 (t,h) pairs x 4 threads each over 256 dims
    int pair = tid >> 2, sub = tid & 3;
    int t = pair >> 2, hh = pair & 3;
    float s = 0.f;
    for (int d = sub * 256; d < sub * 256 + 256; d++)
      s += bf2f(xs[t * 1024 + d]) * wpool[hh * 1024 + d];
    s += __shfl_down(s, 2, 64);
    s += __shfl_down(s, 1, 64);
    if (sub == 0) {
      float temp = fmaxf(tptr[0], 0.01f);
      lg[hh][t] = s / temp;
    }
  }
  __syncthreads();
  if (tid < 4) {  // softmax over t
    int hh = tid;
    float m = -1e30f;
    for (int t = 0; t < 16; t++) m = fmaxf(m, lg[hh][t]);
    float p[16], sum = 0.f;
    for (int t = 0; t < 16; t++) { p[t] = __expf(lg[hh][t] - m); sum += p[t]; }
    float inv = 1.f / sum;
    for (int t = 0; t < 16; t++) aw[hh][t] = p[t] * inv;
  }
  __syncthreads();
  for (int c = tid; c < 1024; c += 256) {
    int hh = c >> 8;
    float o = 0.f;
    #pragma unroll
    for (int t = 0; t < 16; t++) o += aw[hh][t] * bf2f(xs[t * 1024 + c]);
    pooled[(size_t)patch * 1024 + c] = o;
  }
}

extern "C" void kernel_launch(void* const* d_in, const int* in_sizes, int n_in,
                              void* d_out, int out_size, void* d_ws, size_t ws_size,
                              hipStream_t stream) {
  (void)in_sizes; (void)n_in; (void)out_size; (void)ws_size;
  const float* pbe  = (const float*)d_in[0];   // (4,512,16,1024)
  const float* lpos = (const float*)d_in[1];   // (16,1024)
  const float* wg   = (const float*)d_in[2];
  const float* wi   = (const float*)d_in[3];
  const float* cw   = (const float*)d_in[4];   // (1024,1,5)
  const float* wqkv = (const float*)d_in[5];   // (3072,1024)
  const float* wio  = (const float*)d_in[6];
  const float* wpl  = (const float*)d_in[7];   // (4,1024)
  const float* temp = (const float*)d_in[8];
  const float* wup  = (const float*)d_in[9];
  const float* wdn  = (const float*)d_in[10];
  const float* wout = (const float*)d_in[11];
  float* outp = (float*)d_out;                 // (4,512,1024) fp32

  const int ROWS = 32768, Dm = 1024, NPAT = 2048;

  char* p = (char*)d_ws;
  auto take = [&](size_t nbytes) { void* r = (void*)p; p += (nbytes + 255) & ~(size_t)255; return r; };
  unsigned short* wg_b   = (unsigned short*)take((size_t)Dm * Dm * 2);
  unsigned short* wi_b   = (unsigned short*)take((size_t)Dm * Dm * 2);
  unsigned short* wqkv_b = (unsigned short*)take((size_t)3 * Dm * Dm * 2);
  unsigned short* wio_b  = (unsigned short*)take((size_t)Dm * Dm * 2);
  unsigned short* wup_b  = (unsigned short*)take((size_t)Dm * Dm * 2);
  unsigned short* wdn_b  = (unsigned short*)take((size_t)Dm * Dm * 2);
  unsigned short* wout_b = (unsigned short*)take((size_t)Dm * Dm * 2);
  unsigned short* slotA  = (unsigned short*)take((size_t)ROWS * Dm * 2);  // xn / x2n / x4
  unsigned short* slotB  = (unsigned short*)take((size_t)ROWS * Dm * 2);  // h / sa
  unsigned short* slotC  = (unsigned short*)take((size_t)ROWS * Dm * 2);  // x2 / x3
  unsigned short* qkvB   = (unsigned short*)take((size_t)ROWS * 3 * Dm * 2);
  float*          pooled = (float*)take((size_t)NPAT * Dm * 4);
  unsigned short* pooledn= (unsigned short*)take((size_t)NPAT * Dm * 2);
  unsigned short* ubuf   = (unsigned short*)take((size_t)NPAT * Dm * 2);
  unsigned short* y1b    = (unsigned short*)take((size_t)NPAT * Dm * 2);
  float*          y2     = (float*)take((size_t)NPAT * Dm * 4);

  // 0. all weight conversions in one launch
  CvtArgs ca;
  ca.src[0] = wg;   ca.dst[0] = wg_b;
  ca.src[1] = wi;   ca.dst[1] = wi_b;
  ca.src[2] = wqkv; ca.dst[2] = wqkv_b;
  ca.src[3] = wio;  ca.dst[3] = wio_b;
  ca.src[4] = wup;  ca.dst[4] = wup_b;
  ca.src[5] = wdn;  ca.dst[5] = wdn_b;
  ca.src[6] = wout; ca.dst[6] = wout_b;
  int off = 0;
  for (int i = 0; i < 7; i++) { ca.blkoff[i] = off; off += (i == 2) ? 3072 : 1024; }
  ca.blkoff[7] = off;
  cvt_all<<<dim3(off), dim3(256), 0, stream>>>(ca);

  // 1. xn = rmsnorm(pbe + pos)
  prep_kernel<<<dim3(ROWS), dim3(256), 0, stream>>>(pbe, lpos, slotA);
  // 2. h = silu(xn@wg^T) * (xn@wi^T)
  gemm_dual<<<dim3(ROWS / 128, Dm / 128), dim3(256), 0, stream>>>(
      slotA, wg_b, wi_b, ROWS, Dm, Dm, slotB);
  // 3+4. x2 = h + conv(h); x2n = rmsnorm(x2)
  conv_rms_kernel<<<dim3(NPAT), dim3(256), 0, stream>>>(slotB, cw, slotC, slotA);
  // 5. qkv = x2n @ wqkv^T
  gemm_bt<1><<<dim3(ROWS / 128, 3 * Dm / 128), dim3(256), 0, stream>>>(
      slotA, wqkv_b, ROWS, 3 * Dm, Dm, nullptr, qkvB, nullptr, nullptr);
  // 6. sa = attention(qkv)
  attn_kernel<<<dim3(NPAT, 4), dim3(256), 0, stream>>>(qkvB, slotB);
  // 7. x3 = x2 + sa @ wio^T   (in-place into slotC)
  gemm_bt<3><<<dim3(ROWS / 128, Dm / 128), dim3(256), 0, stream>>>(
      slotB, wio_b, ROWS, Dm, Dm, nullptr, slotC, slotC, nullptr);
  // 8. x4 = rmsnorm(x3)
  rmsnorm_kernel<unsigned short, unsigned short><<<dim3(ROWS), dim3(256), 0, stream>>>(slotC, slotA);
  // 9. pooled = headwise softmax-pool(x4)
  pool_kernel<<<dim3(NPAT), dim3(256), 0, stream>>>(slotA, wpl, temp, pooled);
  // 10. pooledn = rmsnorm(pooled)
  rmsnorm_kernel<float, unsigned short><<<dim3(NPAT), dim3(256), 0, stream>>>(pooled, pooledn);
  // 11. u = silu(pooledn @ wup^T)
  gemm_bt<2><<<dim3(NPAT / 128, Dm / 128), dim3(256), 0, stream>>>(
      pooledn, wup_b, NPAT, Dm, Dm, nullptr, ubuf, nullptr, nullptr);
  // 12. y1 = pooled + u @ wdn^T
  gemm_bt<4><<<dim3(NPAT / 128, Dm / 128), dim3(256), 0, stream>>>(
      ubuf, wdn_b, NPAT, Dm, Dm, nullptr, y1b, nullptr, pooled);
  // 13. y2 = y1 @ wout^T
  gemm_bt<0><<<dim3(NPAT / 128, Dm / 128), dim3(256), 0, stream>>>(
      y1b, wout_b, NPAT, Dm, Dm, y2, nullptr, nullptr, nullptr);
  // 14. out = rmsnorm(y2)
  rmsnorm_kernel<float, float><<<dim3(NPAT), dim3(256), 0, stream>>>(y2, outp);
}

// Round 3
// 1178.520 us; speedup vs baseline: 1.1925x; 1.1839x over previous
//
#include <hip/hip_runtime.h>
#include <cstdint>
#include <cstddef>

// Shapes: B=4, NP=512, PS=16, D=1024, NH=4, HD=256, PH=4, PHD=256, K=5
// Rows of activation matrix: B*NP*PS = 32768. Patches: B*NP = 2048.

typedef __bf16 bf16x8 __attribute__((ext_vector_type(8)));
typedef float floatx4 __attribute__((ext_vector_type(4)));

#define DEV static __device__ __forceinline__

DEV unsigned short f2bf(float f) {
  union { float f; unsigned u; } x; x.f = f;
  unsigned r = x.u + 0x7fffu + ((x.u >> 16) & 1u);  // RNE
  return (unsigned short)(r >> 16);
}
DEV float bf2f(unsigned short b) {
  union { unsigned u; float f; } x; x.u = ((unsigned)b) << 16;
  return x.f;
}
DEV float silu_f(float v) { return v / (1.f + __expf(-v)); }

// async global->LDS, 16 bytes per lane. LDS dest is wave-uniform base + lane*16.
DEV void gl_lds16(const unsigned short* g, unsigned short* l) {
  __builtin_amdgcn_global_load_lds(
      (const __attribute__((address_space(1))) void*)g,
      (__attribute__((address_space(3))) void*)l, 16, 0, 0);
}

// block = 256 threads (4 waves); returns full-block sum to all threads
DEV float block_reduce_sum(float v) {
  #pragma unroll
  for (int o = 32; o > 0; o >>= 1) v += __shfl_down(v, o, 64);
  __shared__ float s[4];
  int w = threadIdx.x >> 6;
  if ((threadIdx.x & 63) == 0) s[w] = v;
  __syncthreads();
  return s[0] + s[1] + s[2] + s[3];
}

// ---------------- weight convert fp32 -> bf16 (all weights, one launch) -----
struct CvtArgs {
  const float* src[7];
  unsigned short* dst[7];
  int blkoff[8];  // block ranges per weight (1024 elems per block)
};
__global__ __launch_bounds__(256) void cvt_all(CvtArgs a) {
  int b = blockIdx.x;
  int w = 0;
  #pragma unroll
  for (int i = 0; i < 6; i++) w += (b >= a.blkoff[i + 1]) ? 1 : 0;
  int i = (b - a.blkoff[w]) * 1024 + threadIdx.x * 4;
  float4 v = *(const float4*)(a.src[w] + i);
  ushort4 o;
  o.x = f2bf(v.x); o.y = f2bf(v.y); o.z = f2bf(v.z); o.w = f2bf(v.w);
  *(ushort4*)(a.dst[w] + i) = o;
}

// ---------------- x = rmsnorm(pbe + local_pos) -> bf16 ----------------
__global__ __launch_bounds__(256) void prep_kernel(const float* __restrict__ pbe,
                                                   const float* __restrict__ pos,
                                                   unsigned short* __restrict__ xn) {
  int row = blockIdx.x;              // 0..32767
  int t = row & 15;                  // position within patch
  const float* ip = pbe + (size_t)row * 1024;
  const float* pp = pos + (size_t)t * 1024;
  int c = threadIdx.x * 4;
  float4 v = *(const float4*)(ip + c);
  float4 p = *(const float4*)(pp + c);
  v.x += p.x; v.y += p.y; v.z += p.z; v.w += p.w;
  float ss = v.x * v.x + v.y * v.y + v.z * v.z + v.w * v.w;
  ss = block_reduce_sum(ss);
  float sc = rsqrtf(ss * (1.f / 1024.f) + 1.1920929e-7f);
  ushort4 o;
  o.x = f2bf(v.x * sc); o.y = f2bf(v.y * sc); o.z = f2bf(v.z * sc); o.w = f2bf(v.w * sc);
  *(ushort4*)(xn + (size_t)row * 1024 + c) = o;
}

// ---------------- generic rmsnorm over D=1024 ----------------
DEV float ldval(const float* p, size_t i) { return p[i]; }
DEV float ldval(const unsigned short* p, size_t i) { return bf2f(p[i]); }
DEV void stval(float* p, size_t i, float v) { p[i] = v; }
DEV void stval(unsigned short* p, size_t i, float v) { p[i] = f2bf(v); }

template <typename TI, typename TO>
__global__ __launch_bounds__(256) void rmsnorm_kernel(const TI* __restrict__ in,
                                                      TO* __restrict__ out) {
  size_t row = blockIdx.x;
  const TI* ip = in + row * 1024;
  TO* op = out + row * 1024;
  int c = threadIdx.x * 4;
  float v[4]; float ss = 0.f;
  #pragma unroll
  for (int j = 0; j < 4; j++) { v[j] = ldval(ip, c + j); ss += v[j] * v[j]; }
  ss = block_reduce_sum(ss);
  float sc = rsqrtf(ss * (1.f / 1024.f) + 1.1920929e-7f);
  #pragma unroll
  for (int j = 0; j < 4; j++) stval(op, c + j, v[j] * sc);
}

// ============ GEMM core: m97-style global_load_lds staging ============
// LDS tile rows of 32 elems (64 B/row), unpadded. XOR swizzle on the GLOBAL
// side: lane (i%4) loads chunk (i%4)^((row>>1)&3); fragment reads then hit
// each bank-quad exactly 2-way (free per m136). SQ_LDS_BANK_CONFLICT=0 (R2).

// stage one 128x32 tile: each wave issues 2x 1KiB DMA (rows wave*32..+31)
DEV void stage_tile(const unsigned short* __restrict__ src, size_t ld,
                    unsigned short* lds, int wave, int lane, int k0) {
  int r0 = wave * 32 + (lane >> 2);
  int r1 = r0 + 16;
  int c0 = (lane & 3) ^ ((r0 >> 1) & 3);
  int c1 = (lane & 3) ^ ((r1 >> 1) & 3);
  gl_lds16(src + (size_t)r0 * ld + k0 + c0 * 8, lds + wave * 1024);
  gl_lds16(src + (size_t)r1 * ld + k0 + c1 * 8, lds + wave * 1024 + 512);
}
// stage one 64x32 tile: each wave issues 1x 1KiB DMA (rows wave*16..+15)
DEV void stage_tile64(const unsigned short* __restrict__ src, size_t ld,
                      unsigned short* lds, int wave, int lane, int k0) {
  int r = wave * 16 + (lane >> 2);
  int c = (lane & 3) ^ ((r >> 1) & 3);
  gl_lds16(src + (size_t)r * ld + k0 + c * 8, lds + wave * 512);
}
// LDS elem offset of fragment (row, quad)
DEV int frag_off(int row, int quad) {
  return row * 32 + ((quad ^ ((row >> 1) & 3)) * 8);
}

// C[M,N] = A[M,K] @ W[N,K]^T (bf16 in, fp32 acc). Grid: (N/128, M/128) —
// N-tile fastest so XCD round-robin shares the A-stripe (L2/L3 locality).
// EPI: 0=store fp32, 1=store bf16, 2=silu->bf16, 3=+res(bf16)->bf16, 4=+res(fp32)->bf16
template <int EPI>
__global__ __launch_bounds__(256) void gemm_bt(
    const unsigned short* __restrict__ A, const unsigned short* __restrict__ Bw,
    int M, int N, int K,
    float* __restrict__ outF, unsigned short* __restrict__ outB,
    const unsigned short* __restrict__ resB, const float* __restrict__ resF) {
  __shared__ __align__(16) unsigned short As[128 * 32];
  __shared__ __align__(16) unsigned short Bs[128 * 32];
  const int tid = threadIdx.x;
  const int bm = blockIdx.y * 128, bn = blockIdx.x * 128;
  const int wave = tid >> 6, lane = tid & 63;
  const int wy = wave >> 1, wx = wave & 1;
  const int l15 = lane & 15, quad = lane >> 4;

  floatx4 acc[4][4];
  #pragma unroll
  for (int i = 0; i < 4; i++)
    #pragma unroll
    for (int j = 0; j < 4; j++)
      #pragma unroll
      for (int r = 0; r < 4; r++) acc[i][j][r] = 0.f;

  const unsigned short* Ab = A + (size_t)bm * K;
  const unsigned short* Bb = Bw + (size_t)bn * K;
  int aoff[4], boff[4];
  #pragma unroll
  for (int i = 0; i < 4; i++) {
    aoff[i] = frag_off(wy * 64 + i * 16 + l15, quad);
    boff[i] = frag_off(wx * 64 + i * 16 + l15, quad);
  }

  for (int k0 = 0; k0 < K; k0 += 32) {
    __syncthreads();                       // previous tile's reads done
    stage_tile(Ab, K, As, wave, lane, k0);
    stage_tile(Bb, K, Bs, wave, lane, k0);
    __syncthreads();                       // staging complete (vmcnt drained)
    bf16x8 afr[4], bfr[4];
    #pragma unroll
    for (int i = 0; i < 4; i++) afr[i] = *(const bf16x8*)&As[aoff[i]];
    #pragma unroll
    for (int j = 0; j < 4; j++) bfr[j] = *(const bf16x8*)&Bs[boff[j]];
    #pragma unroll
    for (int i = 0; i < 4; i++)
      #pragma unroll
      for (int j = 0; j < 4; j++)
        acc[i][j] = __builtin_amdgcn_mfma_f32_16x16x32_bf16(afr[i], bfr[j], acc[i][j], 0, 0, 0);
  }

  #pragma unroll
  for (int i = 0; i < 4; i++)
    #pragma unroll
    for (int j = 0; j < 4; j++) {
      int gm = bm + wy * 64 + i * 16 + quad * 4;
      int gn = bn + wx * 64 + j * 16 + l15;
      #pragma unroll
      for (int r = 0; r < 4; r++) {
        float v = acc[i][j][r];
        size_t idx = (size_t)(gm + r) * N + gn;
        if (EPI == 0) outF[idx] = v;
        else if (EPI == 1) outB[idx] = f2bf(v);
        else if (EPI == 2) outB[idx] = f2bf(silu_f(v));
        else if (EPI == 3) outB[idx] = f2bf(v + bf2f(resB[idx]));
        else if (EPI == 4) outB[idx] = f2bf(v + resF[idx]);
      }
    }
}

// -------- fused dual GEMM: h = silu(A@Wg^T) * (A@Wi^T) -> bf16 --------
// Block tile 128(M) x 64(N); each wave 64x32 per output -> 64 acc regs
// (R2's 128-acc version hit 1 wave/SIMD, 11.9% occupancy). Grid (N/64, M/128).
__global__ __launch_bounds__(256, 2) void gemm_dual(
    const unsigned short* __restrict__ A, const unsigned short* __restrict__ Bg,
    const unsigned short* __restrict__ Bi, int M, int N, int K,
    unsigned short* __restrict__ outH) {
  __shared__ __align__(16) unsigned short As[128 * 32];
  __shared__ __align__(16) unsigned short Gs[64 * 32];
  __shared__ __align__(16) unsigned short Is[64 * 32];
  const int tid = threadIdx.x;
  const int bm = blockIdx.y * 128, bn = blockIdx.x * 64;
  const int wave = tid >> 6, lane = tid & 63;
  const int wy = wave >> 1, wx = wave & 1;
  const int l15 = lane & 15, quad = lane >> 4;

  floatx4 accg[4][2], acci[4][2];
  #pragma unroll
  for (int i = 0; i < 4; i++)
    #pragma unroll
    for (int j = 0; j < 2; j++)
      #pragma unroll
      for (int r = 0; r < 4; r++) { accg[i][j][r] = 0.f; acci[i][j][r] = 0.f; }

  const unsigned short* Ab = A + (size_t)bm * K;
  const unsigned short* Gb = Bg + (size_t)bn * K;
  const unsigned short* Ib = Bi + (size_t)bn * K;
  int aoff[4], boff[2];
  #pragma unroll
  for (int i = 0; i < 4; i++) aoff[i] = frag_off(wy * 64 + i * 16 + l15, quad);
  #pragma unroll
  for (int j = 0; j < 2; j++) boff[j] = frag_off(wx * 32 + j * 16 + l15, quad);

  for (int k0 = 0; k0 < K; k0 += 32) {
    __syncthreads();
    stage_tile(Ab, K, As, wave, lane, k0);
    stage_tile64(Gb, K, Gs, wave, lane, k0);
    stage_tile64(Ib, K, Is, wave, lane, k0);
    __syncthreads();
    bf16x8 afr[4], gfr[2], ifr[2];
    #pragma unroll
    for (int i = 0; i < 4; i++) afr[i] = *(const bf16x8*)&As[aoff[i]];
    #pragma unroll
    for (int j = 0; j < 2; j++) {
      gfr[j] = *(const bf16x8*)&Gs[boff[j]];
      ifr[j] = *(const bf16x8*)&Is[boff[j]];
    }
    #pragma unroll
    for (int i = 0; i < 4; i++)
      #pragma unroll
      for (int j = 0; j < 2; j++) {
        accg[i][j] = __builtin_amdgcn_mfma_f32_16x16x32_bf16(afr[i], gfr[j], accg[i][j], 0, 0, 0);
        acci[i][j] = __builtin_amdgcn_mfma_f32_16x16x32_bf16(afr[i], ifr[j], acci[i][j], 0, 0, 0);
      }
  }

  #pragma unroll
  for (int i = 0; i < 4; i++)
    #pragma unroll
    for (int j = 0; j < 2; j++) {
      int gm = bm + wy * 64 + i * 16 + quad * 4;
      int gn = bn + wx * 32 + j * 16 + l15;
      #pragma unroll
      for (int r = 0; r < 4; r++) {
        size_t idx = (size_t)(gm + r) * N + gn;
        outH[idx] = f2bf(silu_f(accg[i][j][r]) * acci[i][j][r]);
      }
    }
}

// ------- fused depthwise causal conv (K=5) + residual + rmsnorm -------
// outputs x2 = h + conv(h) and x2n = rmsnorm(x2)
__global__ __launch_bounds__(256) void conv_rms_kernel(const unsigned short* __restrict__ h,
                                                       const float* __restrict__ cw,
                                                       unsigned short* __restrict__ x2,
                                                       unsigned short* __restrict__ x2n) {
  int patch = blockIdx.x;  // 0..2047
  __shared__ __align__(16) unsigned short hs[16 * 1024];
  __shared__ __align__(16) float cws[5120];
  const int tid = threadIdx.x;
  size_t base = (size_t)patch * 16384;
  for (int idx = tid * 8; idx < 16384; idx += 256 * 8)
    *(uint4*)&hs[idx] = *(const uint4*)&h[base + idx];
  for (int i = tid * 4; i < 5120; i += 256 * 4)
    *(float4*)&cws[i] = *(const float4*)&cw[i];
  __syncthreads();
  int t = tid >> 4;
  int lc = (tid & 15) * 8;
  float vals[8][8];
  float ss = 0.f;
  #pragma unroll
  for (int jb = 0; jb < 8; jb++) {
    #pragma unroll
    for (int i = 0; i < 8; i++) {
      int c = jb * 128 + lc + i;
      float acc = bf2f(hs[t * 1024 + c]);  // residual
      #pragma unroll
      for (int k = 0; k < 5; k++) {
        int tt = t + k - 4;
        if (tt >= 0) acc += cws[c * 5 + k] * bf2f(hs[tt * 1024 + c]);
      }
      vals[jb][i] = acc;
      ss += acc * acc;
    }
  }
  ss += __shfl_down(ss, 8, 16);
  ss += __shfl_down(ss, 4, 16);
  ss += __shfl_down(ss, 2, 16);
  ss += __shfl_down(ss, 1, 16);
  ss = __shfl(ss, 0, 16);
  float sc = rsqrtf(ss * (1.f / 1024.f) + 1.1920929e-7f);
  #pragma unroll
  for (int jb = 0; jb < 8; jb++) {
    ushort4 o2[2], on[2];
    #pragma unroll
    for (int i = 0; i < 8; i++) {
      ((unsigned short*)o2)[i] = f2bf(vals[jb][i]);
      ((unsigned short*)on)[i] = f2bf(vals[jb][i] * sc);
    }
    size_t off = base + (size_t)t * 1024 + jb * 128 + lc;
    *(uint4*)&x2[off] = *(uint4*)o2;
    *(uint4*)&x2n[off] = *(uint4*)on;
  }
}

// ---------------- per-patch per-head attention (PS=16, HD=256) ----------------
__global__ __launch_bounds__(256) void attn_kernel(const unsigned short* __restrict__ qkv,
                                                   unsigned short* __restrict__ sa) {
  int patch = blockIdx.x;  // 0..2047
  int head = blockIdx.y;   // 0..3
  const int tid = threadIdx.x;
  __shared__ float qs[16][260], ks[16][260], vs[16][260];
  __shared__ float sc[16][16];
  size_t base = (size_t)patch * 16 * 3072 + (size_t)head * 256;
  for (int idx = tid * 8; idx < 16 * 256; idx += 256 * 8) {
    int t = idx >> 8, d = idx & 255;
    size_t roff = base + (size_t)t * 3072 + d;
    uint4 qv = *(const uint4*)&qkv[roff];
    uint4 kv = *(const uint4*)&qkv[roff + 1024];
    uint4 vv = *(const uint4*)&qkv[roff + 2048];
    const unsigned short* qp = (const unsigned short*)&qv;
    const unsigned short* kp = (const unsigned short*)&kv;
    const unsigned short* vp = (const unsigned short*)&vv;
    #pragma unroll
    for (int i = 0; i < 8; i++) {
      qs[t][d + i] = bf2f(qp[i]);
      ks[t][d + i] = bf2f(kp[i]);
      vs[t][d + i] = bf2f(vp[i]);
    }
  }
  __syncthreads();
  {
    int t = tid >> 4, kk = tid & 15;
    float s = 0.f;
    for (int d = 0; d < 256; d++) s += qs[t][d] * ks[kk][d];
    sc[t][kk] = s * 0.0625f;  // HD^-0.5
  }
  __syncthreads();
  if (tid < 16) {
    float m = -1e30f;
    for (int kk = 0; kk < 16; kk++) m = fmaxf(m, sc[tid][kk]);
    float p[16], sum = 0.f;
    for (int kk = 0; kk < 16; kk++) { p[kk] = __expf(sc[tid][kk] - m); sum += p[kk]; }
    float inv = 1.f / sum;
    for (int kk = 0; kk < 16; kk++) sc[tid][kk] = p[kk] * inv;
  }
  __syncthreads();
  for (int idx = tid * 8; idx < 4096; idx += 256 * 8) {
    int t = idx >> 8, d = idx & 255;
    ushort4 o[2];
    #pragma unroll
    for (int i = 0; i < 8; i++) {
      float v = 0.f;
      #pragma unroll
      for (int kk = 0; kk < 16; kk++) v += sc[t][kk] * vs[kk][d + i];
      ((unsigned short*)o)[i] = f2bf(v);
    }
    *(uint4*)&sa[(size_t)(patch * 16 + t) * 1024 + head * 256 + d] = *(uint4*)o;
  }
}

// ---------------- head pooling: logits -> softmax over t -> weighted sum -----
__global__ __launch_bounds__(256) void pool_kernel(const unsigned short* __restrict__ x4,
                                                   const float* __restrict__ wpool,
                                                   const float* __restrict__ tptr,
                                                   float* __restrict__ pooled) {
  int patch = blockIdx.x;  // 0..2047
  __shared__ __align__(16) unsigned short xs[16 * 1024];
  __shared__ float lg[4][16], aw[4][16];
  const int tid = threadIdx.x;
  size_t base = (size_t)patch * 16384;
  for (int idx = tid * 8; idx < 16384; idx += 256 * 8)
    *(uint4*)&xs[idx] = *(const uint4*)&x4[base + idx];
  __syncthreads();
  {
    int pair = tid >> 2, sub = tid & 3;
    int t = pair >> 2, hh = pair & 3;
    float s = 0.f;
    for (int d = sub * 256; d < sub * 256 + 256; d++)
      s += bf2f(xs[t * 1024 + d]) * wpool[hh * 1024 + d];
    s += __shfl_down(s, 2, 64);
    s += __shfl_down(s, 1, 64);
    if (sub == 0) {
      float temp = fmaxf(tptr[0], 0.01f);
      lg[hh][t] = s / temp;
    }
  }
  __syncthreads();
  if (tid < 4) {
    int hh = tid;
    float m = -1e30f;
    for (int t = 0; t < 16; t++) m = fmaxf(m, lg[hh][t]);
    float p[16], sum = 0.f;
    for (int t = 0; t < 16; t++) { p[t] = __expf(lg[hh][t] - m); sum += p[t]; }
    float inv = 1.f / sum;
    for (int t = 0; t < 16; t++) aw[hh][t] = p[t] * inv;
  }
  __syncthreads();
  for (int c = tid; c < 1024; c += 256) {
    int hh = c >> 8;
    float o = 0.f;
    #pragma unroll
    for (int t = 0; t < 16; t++) o += aw[hh][t] * bf2f(xs[t * 1024 + c]);
    pooled[(size_t)patch * 1024 + c] = o;
  }
}

extern "C" void kernel_launch(void* const* d_in, const int* in_sizes, int n_in,
                              void* d_out, int out_size, void* d_ws, size_t ws_size,
                              hipStream_t stream) {
  (void)in_sizes; (void)n_in; (void)out_size; (void)ws_size;
  const float* pbe  = (const float*)d_in[0];   // (4,512,16,1024)
  const float* lpos = (const float*)d_in[1];   // (16,1024)
  const float* wg   = (const float*)d_in[2];
  const float* wi   = (const float*)d_in[3];
  const float* cw   = (const float*)d_in[4];   // (1024,1,5)
  const float* wqkv = (const float*)d_in[5];   // (3072,1024)
  const float* wio  = (const float*)d_in[6];
  const float* wpl  = (const float*)d_in[7];   // (4,1024)
  const float* temp = (const float*)d_in[8];
  const float* wup  = (const float*)d_in[9];
  const float* wdn  = (const float*)d_in[10];
  const float* wout = (const float*)d_in[11];
  float* outp = (float*)d_out;                 // (4,512,1024) fp32

  const int ROWS = 32768, Dm = 1024, NPAT = 2048;

  char* p = (char*)d_ws;
  auto take = [&](size_t nbytes) { void* r = (void*)p; p += (nbytes + 255) & ~(size_t)255; return r; };
  unsigned short* wg_b   = (unsigned short*)take((size_t)Dm * Dm * 2);
  unsigned short* wi_b   = (unsigned short*)take((size_t)Dm * Dm * 2);
  unsigned short* wqkv_b = (unsigned short*)take((size_t)3 * Dm * Dm * 2);
  unsigned short* wio_b  = (unsigned short*)take((size_t)Dm * Dm * 2);
  unsigned short* wup_b  = (unsigned short*)take((size_t)Dm * Dm * 2);
  unsigned short* wdn_b  = (unsigned short*)take((size_t)Dm * Dm * 2);
  unsigned short* wout_b = (unsigned short*)take((size_t)Dm * Dm * 2);
  unsigned short* slotA  = (unsigned short*)take((size_t)ROWS * Dm * 2);  // xn / x2n / x4
  unsigned short* slotB  = (unsigned short*)take((size_t)ROWS * Dm * 2);  // h / sa
  unsigned short* slotC  = (unsigned short*)take((size_t)ROWS * Dm * 2);  // x2 / x3
  unsigned short* qkvB   = (unsigned short*)take((size_t)ROWS * 3 * Dm * 2);
  float*          pooled = (float*)take((size_t)NPAT * Dm * 4);
  unsigned short* pooledn= (unsigned short*)take((size_t)NPAT * Dm * 2);
  unsigned short* ubuf   = (unsigned short*)take((size_t)NPAT * Dm * 2);
  unsigned short* y1b    = (unsigned short*)take((size_t)NPAT * Dm * 2);
  float*          y2     = (float*)take((size_t)NPAT * Dm * 4);

  // 0. all weight conversions in one launch
  CvtArgs ca;
  ca.src[0] = wg;   ca.dst[0] = wg_b;
  ca.src[1] = wi;   ca.dst[1] = wi_b;
  ca.src[2] = wqkv; ca.dst[2] = wqkv_b;
  ca.src[3] = wio;  ca.dst[3] = wio_b;
  ca.src[4] = wup;  ca.dst[4] = wup_b;
  ca.src[5] = wdn;  ca.dst[5] = wdn_b;
  ca.src[6] = wout; ca.dst[6] = wout_b;
  int off = 0;
  for (int i = 0; i < 7; i++) { ca.blkoff[i] = off; off += (i == 2) ? 3072 : 1024; }
  ca.blkoff[7] = off;
  cvt_all<<<dim3(off), dim3(256), 0, stream>>>(ca);

  // 1. xn = rmsnorm(pbe + pos)
  prep_kernel<<<dim3(ROWS), dim3(256), 0, stream>>>(pbe, lpos, slotA);
  // 2. h = silu(xn@wg^T) * (xn@wi^T)
  gemm_dual<<<dim3(Dm / 64, ROWS / 128), dim3(256), 0, stream>>>(
      slotA, wg_b, wi_b, ROWS, Dm, Dm, slotB);
  // 3+4. x2 = h + conv(h); x2n = rmsnorm(x2)
  conv_rms_kernel<<<dim3(NPAT), dim3(256), 0, stream>>>(slotB, cw, slotC, slotA);
  // 5. qkv = x2n @ wqkv^T
  gemm_bt<1><<<dim3(3 * Dm / 128, ROWS / 128), dim3(256), 0, stream>>>(
      slotA, wqkv_b, ROWS, 3 * Dm, Dm, nullptr, qkvB, nullptr, nullptr);
  // 6. sa = attention(qkv)
  attn_kernel<<<dim3(NPAT, 4), dim3(256), 0, stream>>>(qkvB, slotB);
  // 7. x3 = x2 + sa @ wio^T   (in-place into slotC)
  gemm_bt<3><<<dim3(Dm / 128, ROWS / 128), dim3(256), 0, stream>>>(
      slotB, wio_b, ROWS, Dm, Dm, nullptr, slotC, slotC, nullptr);
  // 8. x4 = rmsnorm(x3)
  rmsnorm_kernel<unsigned short, unsigned short><<<dim3(ROWS), dim3(256), 0, stream>>>(slotC, slotA);
  // 9. pooled = headwise softmax-pool(x4)
  pool_kernel<<<dim3(NPAT), dim3(256), 0, stream>>>(slotA, wpl, temp, pooled);
  // 10. pooledn = rmsnorm(pooled)
  rmsnorm_kernel<float, unsigned short><<<dim3(NPAT), dim3(256), 0, stream>>>(pooled, pooledn);
  // 11. u = silu(pooledn @ wup^T)
  gemm_bt<2><<<dim3(Dm / 128, NPAT / 128), dim3(256), 0, stream>>>(
      pooledn, wup_b, NPAT, Dm, Dm, nullptr, ubuf, nullptr, nullptr);
  // 12. y1 = pooled + u @ wdn^T
  gemm_bt<4><<<dim3(Dm / 128, NPAT / 128), dim3(256), 0, stream>>>(
      ubuf, wdn_b, NPAT, Dm, Dm, nullptr, y1b, nullptr, pooled);
  // 13. y2 = y1 @ wout^T
  gemm_bt<0><<<dim3(Dm / 128, NPAT / 128), dim3(256), 0, stream>>>(
      y1b, wout_b, NPAT, Dm, Dm, y2, nullptr, nullptr, nullptr);
  // 14. out = rmsnorm(y2)
  rmsnorm_kernel<float, float><<<dim3(NPAT), dim3(256), 0, stream>>>(y2, outp);
}

// Round 4
// 1140.762 us; speedup vs baseline: 1.2320x; 1.0331x over previous
//
#include <hip/hip_runtime.h>
#include <cstdint>
#include <cstddef>

// Shapes: B=4, NP=512, PS=16, D=1024, NH=4, HD=256, PH=4, PHD=256, K=5
// Rows of activation matrix: B*NP*PS = 32768. Patches: B*NP = 2048.

typedef __bf16 bf16x8 __attribute__((ext_vector_type(8)));
typedef float floatx4 __attribute__((ext_vector_type(4)));

#define DEV static __device__ __forceinline__

DEV unsigned short f2bf(float f) {
  union { float f; unsigned u; } x; x.f = f;
  unsigned r = x.u + 0x7fffu + ((x.u >> 16) & 1u);  // RNE
  return (unsigned short)(r >> 16);
}
DEV float bf2f(unsigned short b) {
  union { unsigned u; float f; } x; x.u = ((unsigned)b) << 16;
  return x.f;
}
DEV float silu_f(float v) { return v / (1.f + __expf(-v)); }

// async global->LDS, 16 bytes per lane. LDS dest is wave-uniform base + lane*16.
DEV void gl_lds16(const unsigned short* g, unsigned short* l) {
  __builtin_amdgcn_global_load_lds(
      (const __attribute__((address_space(1))) void*)g,
      (__attribute__((address_space(3))) void*)l, 16, 0, 0);
}

// block = 256 threads (4 waves); returns full-block sum to all threads
DEV float block_reduce_sum(float v) {
  #pragma unroll
  for (int o = 32; o > 0; o >>= 1) v += __shfl_down(v, o, 64);
  __shared__ float s[4];
  int w = threadIdx.x >> 6;
  if ((threadIdx.x & 63) == 0) s[w] = v;
  __syncthreads();
  return s[0] + s[1] + s[2] + s[3];
}

// ---------------- weight convert fp32 -> bf16 (all weights, one launch) -----
struct CvtArgs {
  const float* src[7];
  unsigned short* dst[7];
  int blkoff[8];  // block ranges per weight (1024 elems per block)
};
__global__ __launch_bounds__(256) void cvt_all(CvtArgs a) {
  int b = blockIdx.x;
  int w = 0;
  #pragma unroll
  for (int i = 0; i < 6; i++) w += (b >= a.blkoff[i + 1]) ? 1 : 0;
  int i = (b - a.blkoff[w]) * 1024 + threadIdx.x * 4;
  float4 v = *(const float4*)(a.src[w] + i);
  ushort4 o;
  o.x = f2bf(v.x); o.y = f2bf(v.y); o.z = f2bf(v.z); o.w = f2bf(v.w);
  *(ushort4*)(a.dst[w] + i) = o;
}

// ---------------- x = rmsnorm(pbe + local_pos) -> bf16 ----------------
__global__ __launch_bounds__(256) void prep_kernel(const float* __restrict__ pbe,
                                                   const float* __restrict__ pos,
                                                   unsigned short* __restrict__ xn) {
  int row = blockIdx.x;              // 0..32767
  int t = row & 15;                  // position within patch
  const float* ip = pbe + (size_t)row * 1024;
  const float* pp = pos + (size_t)t * 1024;
  int c = threadIdx.x * 4;
  float4 v = *(const float4*)(ip + c);
  float4 p = *(const float4*)(pp + c);
  v.x += p.x; v.y += p.y; v.z += p.z; v.w += p.w;
  float ss = v.x * v.x + v.y * v.y + v.z * v.z + v.w * v.w;
  ss = block_reduce_sum(ss);
  float sc = rsqrtf(ss * (1.f / 1024.f) + 1.1920929e-7f);
  ushort4 o;
  o.x = f2bf(v.x * sc); o.y = f2bf(v.y * sc); o.z = f2bf(v.z * sc); o.w = f2bf(v.w * sc);
  *(ushort4*)(xn + (size_t)row * 1024 + c) = o;
}

// ---------------- generic rmsnorm over D=1024 ----------------
DEV float ldval(const float* p, size_t i) { return p[i]; }
DEV float ldval(const unsigned short* p, size_t i) { return bf2f(p[i]); }
DEV void stval(float* p, size_t i, float v) { p[i] = v; }
DEV void stval(unsigned short* p, size_t i, float v) { p[i] = f2bf(v); }

template <typename TI, typename TO>
__global__ __launch_bounds__(256) void rmsnorm_kernel(const TI* __restrict__ in,
                                                      TO* __restrict__ out) {
  size_t row = blockIdx.x;
  const TI* ip = in + row * 1024;
  TO* op = out + row * 1024;
  int c = threadIdx.x * 4;
  float v[4]; float ss = 0.f;
  #pragma unroll
  for (int j = 0; j < 4; j++) { v[j] = ldval(ip, c + j); ss += v[j] * v[j]; }
  ss = block_reduce_sum(ss);
  float sc = rsqrtf(ss * (1.f / 1024.f) + 1.1920929e-7f);
  #pragma unroll
  for (int j = 0; j < 4; j++) stval(op, c + j, v[j] * sc);
}

// ============ GEMM core: BK=64, global_load_lds staging ============
// LDS tile rows = 64 elems (128 B), unpadded. XOR swizzle on the GLOBAL side:
// within a row, 16B chunk slot s holds global chunk s^(row&7). Fragment reads
// then hit each bank-group 2-way (free per m136); staging DMA writes are
// lane-contiguous. BK=64 doubles MFMA per barrier-pair vs R3's BK=32.

// stage R rows (R in {64,128}) of a 64-elem-wide tile; 4 waves split rows.
template <int R>
DEV void stage_rows(const unsigned short* __restrict__ src, int ldK,
                    unsigned short* lds, int k0, int wave, int lane) {
  constexpr int PER_WAVE = R / 32;  // DMAs per wave (each DMA = 8 rows)
  #pragma unroll
  for (int d = 0; d < PER_WAVE; d++) {
    int di = wave * PER_WAVE + d;
    int r = di * 8 + (lane >> 3);
    int c = (lane & 7) ^ (r & 7);
    gl_lds16(src + (size_t)r * ldK + k0 + c * 8, lds + di * 512);
  }
}
// LDS elem offset of global chunk g (0..7) at row
DEV int frag_off64(int row, int g) {
  return row * 64 + ((g ^ (row & 7)) * 8);
}

// C[M,N] = A[M,K] @ W[N,K]^T (bf16 in, fp32 acc). Grid: (N/TN, M/TM) —
// N-tile fastest so XCD round-robin shares the A-stripe (L2/L3 locality).
// EPI: 0=store fp32, 1=store bf16, 2=silu->bf16, 3=+res(bf16)->bf16, 4=+res(fp32)->bf16
template <int EPI, int TM, int TN>
__global__ __launch_bounds__(256) void gemm_bt(
    const unsigned short* __restrict__ A, const unsigned short* __restrict__ Bw,
    int M, int N, int K,
    float* __restrict__ outF, unsigned short* __restrict__ outB,
    const unsigned short* __restrict__ resB, const float* __restrict__ resF) {
  constexpr int AI = TM / 32;  // m-frags per wave (wave tile TM/2 x TN/2)
  constexpr int BJ = TN / 32;
  __shared__ __align__(16) unsigned short As[TM * 64];
  __shared__ __align__(16) unsigned short Bs[TN * 64];
  const int tid = threadIdx.x;
  const int bm = blockIdx.y * TM, bn = blockIdx.x * TN;
  const int wave = tid >> 6, lane = tid & 63;
  const int wy = wave >> 1, wx = wave & 1;
  const int l15 = lane & 15, quad = lane >> 4;

  floatx4 acc[AI][BJ];
  #pragma unroll
  for (int i = 0; i < AI; i++)
    #pragma unroll
    for (int j = 0; j < BJ; j++)
      #pragma unroll
      for (int r = 0; r < 4; r++) acc[i][j][r] = 0.f;

  const unsigned short* Ab = A + (size_t)bm * K;
  const unsigned short* Bb = Bw + (size_t)bn * K;
  int arow[AI], brow[BJ];
  #pragma unroll
  for (int i = 0; i < AI; i++) arow[i] = wy * (TM / 2) + i * 16 + l15;
  #pragma unroll
  for (int j = 0; j < BJ; j++) brow[j] = wx * (TN / 2) + j * 16 + l15;

  for (int k0 = 0; k0 < K; k0 += 64) {
    __syncthreads();                       // previous tile's reads done
    stage_rows<TM>(Ab, K, As, k0, wave, lane);
    stage_rows<TN>(Bb, K, Bs, k0, wave, lane);
    __syncthreads();                       // staging complete
    #pragma unroll
    for (int h = 0; h < 2; h++) {          // two K=32 halves
      bf16x8 afr[AI], bfr[BJ];
      #pragma unroll
      for (int i = 0; i < AI; i++) afr[i] = *(const bf16x8*)&As[frag_off64(arow[i], h * 4 + quad)];
      #pragma unroll
      for (int j = 0; j < BJ; j++) bfr[j] = *(const bf16x8*)&Bs[frag_off64(brow[j], h * 4 + quad)];
      #pragma unroll
      for (int i = 0; i < AI; i++)
        #pragma unroll
        for (int j = 0; j < BJ; j++)
          acc[i][j] = __builtin_amdgcn_mfma_f32_16x16x32_bf16(afr[i], bfr[j], acc[i][j], 0, 0, 0);
    }
  }

  #pragma unroll
  for (int i = 0; i < AI; i++)
    #pragma unroll
    for (int j = 0; j < BJ; j++) {
      int gm = bm + wy * (TM / 2) + i * 16 + quad * 4;
      int gn = bn + wx * (TN / 2) + j * 16 + l15;
      #pragma unroll
      for (int r = 0; r < 4; r++) {
        float v = acc[i][j][r];
        size_t idx = (size_t)(gm + r) * N + gn;
        if (EPI == 0) outF[idx] = v;
        else if (EPI == 1) outB[idx] = f2bf(v);
        else if (EPI == 2) outB[idx] = f2bf(silu_f(v));
        else if (EPI == 3) outB[idx] = f2bf(v + bf2f(resB[idx]));
        else if (EPI == 4) outB[idx] = f2bf(v + resF[idx]);
      }
    }
}

// -------- fused dual GEMM: h = silu(A@Wg^T) * (A@Wi^T) -> bf16 --------
// Block tile 128(M) x 64(N); wave 64x32 per output -> 64 acc regs.
__global__ __launch_bounds__(256) void gemm_dual(
    const unsigned short* __restrict__ A, const unsigned short* __restrict__ Bg,
    const unsigned short* __restrict__ Bi, int M, int N, int K,
    unsigned short* __restrict__ outH) {
  __shared__ __align__(16) unsigned short As[128 * 64];
  __shared__ __align__(16) unsigned short Gs[64 * 64];
  __shared__ __align__(16) unsigned short Is[64 * 64];
  const int tid = threadIdx.x;
  const int bm = blockIdx.y * 128, bn = blockIdx.x * 64;
  const int wave = tid >> 6, lane = tid & 63;
  const int wy = wave >> 1, wx = wave & 1;
  const int l15 = lane & 15, quad = lane >> 4;

  floatx4 accg[4][2], acci[4][2];
  #pragma unroll
  for (int i = 0; i < 4; i++)
    #pragma unroll
    for (int j = 0; j < 2; j++)
      #pragma unroll
      for (int r = 0; r < 4; r++) { accg[i][j][r] = 0.f; acci[i][j][r] = 0.f; }

  const unsigned short* Ab = A + (size_t)bm * K;
  const unsigned short* Gb = Bg + (size_t)bn * K;
  const unsigned short* Ib = Bi + (size_t)bn * K;
  int arow[4], brow[2];
  #pragma unroll
  for (int i = 0; i < 4; i++) arow[i] = wy * 64 + i * 16 + l15;
  #pragma unroll
  for (int j = 0; j < 2; j++) brow[j] = wx * 32 + j * 16 + l15;

  for (int k0 = 0; k0 < K; k0 += 64) {
    __syncthreads();
    stage_rows<128>(Ab, K, As, k0, wave, lane);
    stage_rows<64>(Gb, K, Gs, k0, wave, lane);
    stage_rows<64>(Ib, K, Is, k0, wave, lane);
    __syncthreads();
    #pragma unroll
    for (int h = 0; h < 2; h++) {
      bf16x8 afr[4], gfr[2], ifr[2];
      #pragma unroll
      for (int i = 0; i < 4; i++) afr[i] = *(const bf16x8*)&As[frag_off64(arow[i], h * 4 + quad)];
      #pragma unroll
      for (int j = 0; j < 2; j++) {
        gfr[j] = *(const bf16x8*)&Gs[frag_off64(brow[j], h * 4 + quad)];
        ifr[j] = *(const bf16x8*)&Is[frag_off64(brow[j], h * 4 + quad)];
      }
      #pragma unroll
      for (int i = 0; i < 4; i++)
        #pragma unroll
        for (int j = 0; j < 2; j++) {
          accg[i][j] = __builtin_amdgcn_mfma_f32_16x16x32_bf16(afr[i], gfr[j], accg[i][j], 0, 0, 0);
          acci[i][j] = __builtin_amdgcn_mfma_f32_16x16x32_bf16(afr[i], ifr[j], acci[i][j], 0, 0, 0);
        }
    }
  }

  #pragma unroll
  for (int i = 0; i < 4; i++)
    #pragma unroll
    for (int j = 0; j < 2; j++) {
      int gm = bm + wy * 64 + i * 16 + quad * 4;
      int gn = bn + wx * 32 + j * 16 + l15;
      #pragma unroll
      for (int r = 0; r < 4; r++) {
        size_t idx = (size_t)(gm + r) * N + gn;
        outH[idx] = f2bf(silu_f(accg[i][j][r]) * acci[i][j][r]);
      }
    }
}

// ------- fused depthwise causal conv (K=5) + residual + rmsnorm -------
// outputs x2 = h + conv(h) and x2n = rmsnorm(x2). Vectorized LDS taps.
#define HS_LD 1040  // skewed row stride (elems): 2080 B -> rows shift 8 banks
__global__ __launch_bounds__(256) void conv_rms_kernel(const unsigned short* __restrict__ h,
                                                       const float* __restrict__ cw,
                                                       unsigned short* __restrict__ x2,
                                                       unsigned short* __restrict__ x2n) {
  int patch = blockIdx.x;  // 0..2047
  __shared__ __align__(16) unsigned short hs[16 * HS_LD];
  __shared__ __align__(16) float cwp[5 * 1024];  // [k][c] planes
  const int tid = threadIdx.x;
  size_t base = (size_t)patch * 16384;
  for (int idx = tid * 8; idx < 16384; idx += 256 * 8) {
    int row = idx >> 10, col = idx & 1023;
    *(uint4*)&hs[row * HS_LD + col] = *(const uint4*)&h[base + idx];
  }
  for (int i = tid; i < 5120; i += 256) {
    int c = i / 5, k = i - c * 5;
    cwp[k * 1024 + c] = cw[i];
  }
  __syncthreads();
  int t = tid >> 4;
  int lc = (tid & 15) * 8;
  float vals[8][8];
  float ss = 0.f;
  #pragma unroll
  for (int jb = 0; jb < 8; jb++) {
    int c = jb * 128 + lc;
    float tap[5][8];
    #pragma unroll
    for (int k = 0; k < 5; k++) {
      int tt = t + k - 4;
      if (tt >= 0) {
        uint4 v = *(const uint4*)&hs[tt * HS_LD + c];
        const unsigned short* vp = (const unsigned short*)&v;
        #pragma unroll
        for (int i = 0; i < 8; i++) tap[k][i] = bf2f(vp[i]);
      } else {
        #pragma unroll
        for (int i = 0; i < 8; i++) tap[k][i] = 0.f;
      }
    }
    float w[5][8];
    #pragma unroll
    for (int k = 0; k < 5; k++) {
      float4 a = *(const float4*)&cwp[k * 1024 + c];
      float4 b = *(const float4*)&cwp[k * 1024 + c + 4];
      w[k][0] = a.x; w[k][1] = a.y; w[k][2] = a.z; w[k][3] = a.w;
      w[k][4] = b.x; w[k][5] = b.y; w[k][6] = b.z; w[k][7] = b.w;
    }
    #pragma unroll
    for (int i = 0; i < 8; i++) {
      float acc = tap[4][i];  // residual (tap k=4 is row t itself)
      #pragma unroll
      for (int k = 0; k < 5; k++) acc += w[k][i] * tap[k][i];
      vals[jb][i] = acc;
      ss += acc * acc;
    }
  }
  ss += __shfl_down(ss, 8, 16);
  ss += __shfl_down(ss, 4, 16);
  ss += __shfl_down(ss, 2, 16);
  ss += __shfl_down(ss, 1, 16);
  ss = __shfl(ss, 0, 16);
  float sc = rsqrtf(ss * (1.f / 1024.f) + 1.1920929e-7f);
  #pragma unroll
  for (int jb = 0; jb < 8; jb++) {
    ushort4 o2[2], on[2];
    #pragma unroll
    for (int i = 0; i < 8; i++) {
      ((unsigned short*)o2)[i] = f2bf(vals[jb][i]);
      ((unsigned short*)on)[i] = f2bf(vals[jb][i] * sc);
    }
    size_t off = base + (size_t)t * 1024 + jb * 128 + lc;
    *(uint4*)&x2[off] = *(uint4*)o2;
    *(uint4*)&x2n[off] = *(uint4*)on;
  }
}

// ---------------- per-patch per-head attention (PS=16, HD=256) ----------------
__global__ __launch_bounds__(256) void attn_kernel(const unsigned short* __restrict__ qkv,
                                                   unsigned short* __restrict__ sa) {
  int patch = blockIdx.x;  // 0..2047
  int head = blockIdx.y;   // 0..3
  const int tid = threadIdx.x;
  __shared__ float qs[16][260], ks[16][260], vs[16][260];
  __shared__ float sc[16][16];
  size_t base = (size_t)patch * 16 * 3072 + (size_t)head * 256;
  for (int idx = tid * 8; idx < 16 * 256; idx += 256 * 8) {
    int t = idx >> 8, d = idx & 255;
    size_t roff = base + (size_t)t * 3072 + d;
    uint4 qv = *(const uint4*)&qkv[roff];
    uint4 kv = *(const uint4*)&qkv[roff + 1024];
    uint4 vv = *(const uint4*)&qkv[roff + 2048];
    const unsigned short* qp = (const unsigned short*)&qv;
    const unsigned short* kp = (const unsigned short*)&kv;
    const unsigned short* vp = (const unsigned short*)&vv;
    #pragma unroll
    for (int i = 0; i < 8; i++) {
      qs[t][d + i] = bf2f(qp[i]);
      ks[t][d + i] = bf2f(kp[i]);
      vs[t][d + i] = bf2f(vp[i]);
    }
  }
  __syncthreads();
  {
    int t = tid >> 4, kk = tid & 15;
    float s = 0.f;
    for (int d = 0; d < 256; d += 4) {
      float4 q = *(const float4*)&qs[t][d];
      float4 k = *(const float4*)&ks[kk][d];
      s += q.x * k.x + q.y * k.y + q.z * k.z + q.w * k.w;
    }
    sc[t][kk] = s * 0.0625f;  // HD^-0.5
  }
  __syncthreads();
  if (tid < 16) {
    float m = -1e30f;
    for (int kk = 0; kk < 16; kk++) m = fmaxf(m, sc[tid][kk]);
    float p[16], sum = 0.f;
    for (int kk = 0; kk < 16; kk++) { p[kk] = __expf(sc[tid][kk] - m); sum += p[kk]; }
    float inv = 1.f / sum;
    for (int kk = 0; kk < 16; kk++) sc[tid][kk] = p[kk] * inv;
  }
  __syncthreads();
  for (int idx = tid * 8; idx < 4096; idx += 256 * 8) {
    int t = idx >> 8, d = idx & 255;
    float o[8] = {0, 0, 0, 0, 0, 0, 0, 0};
    #pragma unroll
    for (int kk = 0; kk < 16; kk++) {
      float w = sc[t][kk];
      float4 v0 = *(const float4*)&vs[kk][d];
      float4 v1 = *(const float4*)&vs[kk][d + 4];
      o[0] += w * v0.x; o[1] += w * v0.y; o[2] += w * v0.z; o[3] += w * v0.w;
      o[4] += w * v1.x; o[5] += w * v1.y; o[6] += w * v1.z; o[7] += w * v1.w;
    }
    ushort4 ov[2];
    #pragma unroll
    for (int i = 0; i < 8; i++) ((unsigned short*)ov)[i] = f2bf(o[i]);
    *(uint4*)&sa[(size_t)(patch * 16 + t) * 1024 + head * 256 + d] = *(uint4*)ov;
  }
}

// ------- head pooling + fused rmsnorm(pooled): logits -> softmax -> pool -----
__global__ __launch_bounds__(256) void pool_kernel(const unsigned short* __restrict__ x4,
                                                   const float* __restrict__ wpool,
                                                   const float* __restrict__ tptr,
                                                   float* __restrict__ pooled,
                                                   unsigned short* __restrict__ pooledn) {
  int patch = blockIdx.x;  // 0..2047
  __shared__ __align__(16) unsigned short xs[16 * 1024];
  __shared__ float lg[4][16], aw[4][16];
  const int tid = threadIdx.x;
  size_t base = (size_t)patch * 16384;
  for (int idx = tid * 8; idx < 16384; idx += 256 * 8)
    *(uint4*)&xs[idx] = *(const uint4*)&x4[base + idx];
  __syncthreads();
  {
    int pair = tid >> 2, sub = tid & 3;
    int t = pair >> 2, hh = pair & 3;
    float s = 0.f;
    for (int d = sub * 256; d < sub * 256 + 256; d++)
      s += bf2f(xs[t * 1024 + d]) * wpool[hh * 1024 + d];
    s += __shfl_down(s, 2, 64);
    s += __shfl_down(s, 1, 64);
    if (sub == 0) {
      float temp = fmaxf(tptr[0], 0.01f);
      lg[hh][t] = s / temp;
    }
  }
  __syncthreads();
  if (tid < 4) {
    int hh = tid;
    float m = -1e30f;
    for (int t = 0; t < 16; t++) m = fmaxf(m, lg[hh][t]);
    float p[16], sum = 0.f;
    for (int t = 0; t < 16; t++) { p[t] = __expf(lg[hh][t] - m); sum += p[t]; }
    float inv = 1.f / sum;
    for (int t = 0; t < 16; t++) aw[hh][t] = p[t] * inv;
  }
  __syncthreads();
  float ov[4]; int cs[4];
  float ss = 0.f;
  #pragma unroll
  for (int q = 0; q < 4; q++) {
    int c = tid + q * 256;
    int hh = c >> 8;
    float o = 0.f;
    #pragma unroll
    for (int t = 0; t < 16; t++) o += aw[hh][t] * bf2f(xs[t * 1024 + c]);
    ov[q] = o; cs[q] = c;
    ss += o * o;
  }
  ss = block_reduce_sum(ss);
  float scn = rsqrtf(ss * (1.f / 1024.f) + 1.1920929e-7f);
  #pragma unroll
  for (int q = 0; q < 4; q++) {
    pooled[(size_t)patch * 1024 + cs[q]] = ov[q];
    pooledn[(size_t)patch * 1024 + cs[q]] = f2bf(ov[q] * scn);
  }
}

extern "C" void kernel_launch(void* const* d_in, const int* in_sizes, int n_in,
                              void* d_out, int out_size, void* d_ws, size_t ws_size,
                              hipStream_t stream) {
  (void)in_sizes; (void)n_in; (void)out_size; (void)ws_size;
  const float* pbe  = (const float*)d_in[0];   // (4,512,16,1024)
  const float* lpos = (const float*)d_in[1];   // (16,1024)
  const float* wg   = (const float*)d_in[2];
  const float* wi   = (const float*)d_in[3];
  const float* cw   = (const float*)d_in[4];   // (1024,1,5)
  const float* wqkv = (const float*)d_in[5];   // (3072,1024)
  const float* wio  = (const float*)d_in[6];
  const float* wpl  = (const float*)d_in[7];   // (4,1024)
  const float* temp = (const float*)d_in[8];
  const float* wup  = (const float*)d_in[9];
  const float* wdn  = (const float*)d_in[10];
  const float* wout = (const float*)d_in[11];
  float* outp = (float*)d_out;                 // (4,512,1024) fp32

  const int ROWS = 32768, Dm = 1024, NPAT = 2048;

  char* p = (char*)d_ws;
  auto take = [&](size_t nbytes) { void* r = (void*)p; p += (nbytes + 255) & ~(size_t)255; return r; };
  unsigned short* wg_b   = (unsigned short*)take((size_t)Dm * Dm * 2);
  unsigned short* wi_b   = (unsigned short*)take((size_t)Dm * Dm * 2);
  unsigned short* wqkv_b = (unsigned short*)take((size_t)3 * Dm * Dm * 2);
  unsigned short* wio_b  = (unsigned short*)take((size_t)Dm * Dm * 2);
  unsigned short* wup_b  = (unsigned short*)take((size_t)Dm * Dm * 2);
  unsigned short* wdn_b  = (unsigned short*)take((size_t)Dm * Dm * 2);
  unsigned short* wout_b = (unsigned short*)take((size_t)Dm * Dm * 2);
  unsigned short* slotA  = (unsigned short*)take((size_t)ROWS * Dm * 2);  // xn / x2n / x4
  unsigned short* slotB  = (unsigned short*)take((size_t)ROWS * Dm * 2);  // h / sa
  unsigned short* slotC  = (unsigned short*)take((size_t)ROWS * Dm * 2);  // x2 / x3
  unsigned short* qkvB   = (unsigned short*)take((size_t)ROWS * 3 * Dm * 2);
  float*          pooled = (float*)take((size_t)NPAT * Dm * 4);
  unsigned short* pooledn= (unsigned short*)take((size_t)NPAT * Dm * 2);
  unsigned short* ubuf   = (unsigned short*)take((size_t)NPAT * Dm * 2);
  unsigned short* y1b    = (unsigned short*)take((size_t)NPAT * Dm * 2);
  float*          y2     = (float*)take((size_t)NPAT * Dm * 4);

  // 0. all weight conversions in one launch
  CvtArgs ca;
  ca.src[0] = wg;   ca.dst[0] = wg_b;
  ca.src[1] = wi;   ca.dst[1] = wi_b;
  ca.src[2] = wqkv; ca.dst[2] = wqkv_b;
  ca.src[3] = wio;  ca.dst[3] = wio_b;
  ca.src[4] = wup;  ca.dst[4] = wup_b;
  ca.src[5] = wdn;  ca.dst[5] = wdn_b;
  ca.src[6] = wout; ca.dst[6] = wout_b;
  int off = 0;
  for (int i = 0; i < 7; i++) { ca.blkoff[i] = off; off += (i == 2) ? 3072 : 1024; }
  ca.blkoff[7] = off;
  cvt_all<<<dim3(off), dim3(256), 0, stream>>>(ca);

  // 1. xn = rmsnorm(pbe + pos)
  prep_kernel<<<dim3(ROWS), dim3(256), 0, stream>>>(pbe, lpos, slotA);
  // 2. h = silu(xn@wg^T) * (xn@wi^T)
  gemm_dual<<<dim3(Dm / 64, ROWS / 128), dim3(256), 0, stream>>>(
      slotA, wg_b, wi_b, ROWS, Dm, Dm, slotB);
  // 3+4. x2 = h + conv(h); x2n = rmsnorm(x2)
  conv_rms_kernel<<<dim3(NPAT), dim3(256), 0, stream>>>(slotB, cw, slotC, slotA);
  // 5. qkv = x2n @ wqkv^T
  gemm_bt<1, 128, 128><<<dim3(3 * Dm / 128, ROWS / 128), dim3(256), 0, stream>>>(
      slotA, wqkv_b, ROWS, 3 * Dm, Dm, nullptr, qkvB, nullptr, nullptr);
  // 6. sa = attention(qkv)
  attn_kernel<<<dim3(NPAT, 4), dim3(256), 0, stream>>>(qkvB, slotB);
  // 7. x3 = x2 + sa @ wio^T   (in-place into slotC)
  gemm_bt<3, 128, 128><<<dim3(Dm / 128, ROWS / 128), dim3(256), 0, stream>>>(
      slotB, wio_b, ROWS, Dm, Dm, nullptr, slotC, slotC, nullptr);
  // 8. x4 = rmsnorm(x3)
  rmsnorm_kernel<unsigned short, unsigned short><<<dim3(ROWS), dim3(256), 0, stream>>>(slotC, slotA);
  // 9+10. pooled = headwise softmax-pool(x4); pooledn = rmsnorm(pooled)
  pool_kernel<<<dim3(NPAT), dim3(256), 0, stream>>>(slotA, wpl, temp, pooled, pooledn);
  // 11. u = silu(pooledn @ wup^T)   (M=2048 -> TM=64 for 256-block grids)
  gemm_bt<2, 64, 128><<<dim3(Dm / 128, NPAT / 64), dim3(256), 0, stream>>>(
      pooledn, wup_b, NPAT, Dm, Dm, nullptr, ubuf, nullptr, nullptr);
  // 12. y1 = pooled + u @ wdn^T
  gemm_bt<4, 64, 128><<<dim3(Dm / 128, NPAT / 64), dim3(256), 0, stream>>>(
      ubuf, wdn_b, NPAT, Dm, Dm, nullptr, y1b, nullptr, pooled);
  // 13. y2 = y1 @ wout^T
  gemm_bt<0, 64, 128><<<dim3(Dm / 128, NPAT / 64), dim3(256), 0, stream>>>(
      y1b, wout_b, NPAT, Dm, Dm, y2, nullptr, nullptr, nullptr);
  // 14. out = rmsnorm(y2)
  rmsnorm_kernel<float, float><<<dim3(NPAT), dim3(256), 0, stream>>>(y2, outp);
}

// Round 5
// 1074.415 us; speedup vs baseline: 1.3080x; 1.0618x over previous
//
#include <hip/hip_runtime.h>
#include <cstdint>
#include <cstddef>

// Shapes: B=4, NP=512, PS=16, D=1024, NH=4, HD=256, PH=4, PHD=256, K=5
// Rows of activation matrix: B*NP*PS = 32768. Patches: B*NP = 2048.

typedef __bf16 bf16x8 __attribute__((ext_vector_type(8)));
typedef float floatx4 __attribute__((ext_vector_type(4)));

#define DEV static __device__ __forceinline__

DEV unsigned short f2bf(float f) {
  union { float f; unsigned u; } x; x.f = f;
  unsigned r = x.u + 0x7fffu + ((x.u >> 16) & 1u);  // RNE
  return (unsigned short)(r >> 16);
}
DEV float bf2f(unsigned short b) {
  union { unsigned u; float f; } x; x.u = ((unsigned)b) << 16;
  return x.f;
}
DEV float silu_f(float v) { return v / (1.f + __expf(-v)); }

// async global->LDS, 16 bytes per lane. LDS dest is wave-uniform base + lane*16.
DEV void gl_lds16(const unsigned short* g, unsigned short* l) {
  __builtin_amdgcn_global_load_lds(
      (const __attribute__((address_space(1))) void*)g,
      (__attribute__((address_space(3))) void*)l, 16, 0, 0);
}

// block = 256 threads (4 waves); returns full-block sum to all threads
DEV float block_reduce_sum(float v) {
  #pragma unroll
  for (int o = 32; o > 0; o >>= 1) v += __shfl_down(v, o, 64);
  __shared__ float s[4];
  int w = threadIdx.x >> 6;
  if ((threadIdx.x & 63) == 0) s[w] = v;
  __syncthreads();
  return s[0] + s[1] + s[2] + s[3];
}

// ---------------- weight convert fp32 -> bf16 (all weights, one launch) -----
struct CvtArgs {
  const float* src[7];
  unsigned short* dst[7];
  int blkoff[8];  // block ranges per weight (1024 elems per block)
};
__global__ __launch_bounds__(256) void cvt_all(CvtArgs a) {
  int b = blockIdx.x;
  int w = 0;
  #pragma unroll
  for (int i = 0; i < 6; i++) w += (b >= a.blkoff[i + 1]) ? 1 : 0;
  int i = (b - a.blkoff[w]) * 1024 + threadIdx.x * 4;
  float4 v = *(const float4*)(a.src[w] + i);
  ushort4 o;
  o.x = f2bf(v.x); o.y = f2bf(v.y); o.z = f2bf(v.z); o.w = f2bf(v.w);
  *(ushort4*)(a.dst[w] + i) = o;
}

// ---------------- x = rmsnorm(pbe + local_pos) -> bf16 ----------------
__global__ __launch_bounds__(256) void prep_kernel(const float* __restrict__ pbe,
                                                   const float* __restrict__ pos,
                                                   unsigned short* __restrict__ xn) {
  int row = blockIdx.x;              // 0..32767
  int t = row & 15;                  // position within patch
  const float* ip = pbe + (size_t)row * 1024;
  const float* pp = pos + (size_t)t * 1024;
  int c = threadIdx.x * 4;
  float4 v = *(const float4*)(ip + c);
  float4 p = *(const float4*)(pp + c);
  v.x += p.x; v.y += p.y; v.z += p.z; v.w += p.w;
  float ss = v.x * v.x + v.y * v.y + v.z * v.z + v.w * v.w;
  ss = block_reduce_sum(ss);
  float sc = rsqrtf(ss * (1.f / 1024.f) + 1.1920929e-7f);
  ushort4 o;
  o.x = f2bf(v.x * sc); o.y = f2bf(v.y * sc); o.z = f2bf(v.z * sc); o.w = f2bf(v.w * sc);
  *(ushort4*)(xn + (size_t)row * 1024 + c) = o;
}

// ---------------- generic rmsnorm over D=1024 ----------------
DEV float ldval(const float* p, size_t i) { return p[i]; }
DEV float ldval(const unsigned short* p, size_t i) { return bf2f(p[i]); }
DEV void stval(float* p, size_t i, float v) { p[i] = v; }
DEV void stval(unsigned short* p, size_t i, float v) { p[i] = f2bf(v); }

template <typename TI, typename TO>
__global__ __launch_bounds__(256) void rmsnorm_kernel(const TI* __restrict__ in,
                                                      TO* __restrict__ out) {
  size_t row = blockIdx.x;
  const TI* ip = in + row * 1024;
  TO* op = out + row * 1024;
  int c = threadIdx.x * 4;
  float v[4]; float ss = 0.f;
  #pragma unroll
  for (int j = 0; j < 4; j++) { v[j] = ldval(ip, c + j); ss += v[j] * v[j]; }
  ss = block_reduce_sum(ss);
  float sc = rsqrtf(ss * (1.f / 1024.f) + 1.1920929e-7f);
  #pragma unroll
  for (int j = 0; j < 4; j++) stval(op, c + j, v[j] * sc);
}

// ============ GEMM: wave-specialized producer/consumer, BK=64 ============
// 512 threads: waves 0-3 compute (2x2 of (TM/2)x(TN/2)), waves 4-7 stage via
// global_load_lds into double-buffered LDS. Producers issue next-tile DMA at
// iter start and drain vmcnt at the barrier WHILE consumers MFMA the current
// buffer -> barrier release = max(DMA, compute), not sum. Consumers issue no
// VMEM, so their barrier entry has no vmcnt wait.
// LDS rows = 64 elems (128 B), XOR swizzle on the GLOBAL side: 16B chunk slot
// s holds global chunk s^(row&7); fragment reads hit banks 2-way (free, m136).

// stage R rows of a 64-elem-wide tile; 4 producer waves (pw 0-3) split rows.
template <int R>
DEV void stage_rows(const unsigned short* __restrict__ src, int ldK,
                    unsigned short* lds, int k0, int pw, int lane) {
  constexpr int PER_WAVE = R / 32;  // DMAs per wave (each DMA = 8 rows)
  #pragma unroll
  for (int d = 0; d < PER_WAVE; d++) {
    int di = pw * PER_WAVE + d;
    int r = di * 8 + (lane >> 3);
    int c = (lane & 7) ^ (r & 7);
    gl_lds16(src + (size_t)r * ldK + k0 + c * 8, lds + di * 512);
  }
}
// LDS elem offset of global chunk g (0..7) at row
DEV int frag_off64(int row, int g) {
  return row * 64 + ((g ^ (row & 7)) * 8);
}

// C[M,N] = A[M,K] @ W[N,K]^T (bf16 in, fp32 acc). Grid: (N/TN, M/TM).
// EPI: 0=store fp32, 1=store bf16, 2=silu->bf16, 3=+res(bf16)->bf16, 4=+res(fp32)->bf16
template <int EPI, int TM, int TN>
__global__ __launch_bounds__(512) void gemm_ws(
    const unsigned short* __restrict__ A, const unsigned short* __restrict__ Bw,
    int M, int N, int K,
    float* __restrict__ outF, unsigned short* __restrict__ outB,
    const unsigned short* __restrict__ resB, const float* __restrict__ resF) {
  constexpr int AI = TM / 32;
  constexpr int BJ = TN / 32;
  __shared__ __align__(16) unsigned short As[2][TM * 64];
  __shared__ __align__(16) unsigned short Bs[2][TN * 64];
  const int tid = threadIdx.x;
  const int bm = blockIdx.y * TM, bn = blockIdx.x * TN;
  const int wave = tid >> 6, lane = tid & 63;
  const bool producer = wave >= 4;
  const int pw = wave & 3;
  const int wy = (wave & 3) >> 1, wx = wave & 1;
  const int l15 = lane & 15, quad = lane >> 4;

  const unsigned short* Ab = A + (size_t)bm * K;
  const unsigned short* Bb = Bw + (size_t)bn * K;

  floatx4 acc[AI][BJ];
  #pragma unroll
  for (int i = 0; i < AI; i++)
    #pragma unroll
    for (int j = 0; j < BJ; j++)
      #pragma unroll
      for (int r = 0; r < 4; r++) acc[i][j][r] = 0.f;

  int arow[AI], brow[BJ];
  #pragma unroll
  for (int i = 0; i < AI; i++) arow[i] = wy * (TM / 2) + i * 16 + l15;
  #pragma unroll
  for (int j = 0; j < BJ; j++) brow[j] = wx * (TN / 2) + j * 16 + l15;

  const int iters = K >> 6;
  if (producer) {
    stage_rows<TM>(Ab, K, As[0], 0, pw, lane);
    stage_rows<TN>(Bb, K, Bs[0], 0, pw, lane);
  }
  __syncthreads();
  for (int it = 0; it < iters; ++it) {
    const int cur = it & 1;
    if (producer) {
      if (it + 1 < iters) {
        stage_rows<TM>(Ab, K, As[cur ^ 1], (it + 1) << 6, pw, lane);
        stage_rows<TN>(Bb, K, Bs[cur ^ 1], (it + 1) << 6, pw, lane);
      }
    } else {
      #pragma unroll
      for (int h = 0; h < 2; h++) {
        bf16x8 afr[AI], bfr[BJ];
        #pragma unroll
        for (int i = 0; i < AI; i++)
          afr[i] = *(const bf16x8*)&As[cur][frag_off64(arow[i], h * 4 + quad)];
        #pragma unroll
        for (int j = 0; j < BJ; j++)
          bfr[j] = *(const bf16x8*)&Bs[cur][frag_off64(brow[j], h * 4 + quad)];
        #pragma unroll
        for (int i = 0; i < AI; i++)
          #pragma unroll
          for (int j = 0; j < BJ; j++)
            acc[i][j] = __builtin_amdgcn_mfma_f32_16x16x32_bf16(afr[i], bfr[j], acc[i][j], 0, 0, 0);
      }
    }
    __syncthreads();
  }

  if (producer) return;
  #pragma unroll
  for (int i = 0; i < AI; i++)
    #pragma unroll
    for (int j = 0; j < BJ; j++) {
      int gm = bm + wy * (TM / 2) + i * 16 + quad * 4;
      int gn = bn + wx * (TN / 2) + j * 16 + l15;
      #pragma unroll
      for (int r = 0; r < 4; r++) {
        float v = acc[i][j][r];
        size_t idx = (size_t)(gm + r) * N + gn;
        if (EPI == 0) outF[idx] = v;
        else if (EPI == 1) outB[idx] = f2bf(v);
        else if (EPI == 2) outB[idx] = f2bf(silu_f(v));
        else if (EPI == 3) outB[idx] = f2bf(v + bf2f(resB[idx]));
        else if (EPI == 4) outB[idx] = f2bf(v + resF[idx]);
      }
    }
}

// ---- wave-specialized dual GEMM: h = silu(A@Wg^T) * (A@Wi^T) -> bf16 ----
// Block tile 128(M) x 64(N); consumer wave 64x32 per output (64 acc regs).
__global__ __launch_bounds__(512) void gemm_dual_ws(
    const unsigned short* __restrict__ A, const unsigned short* __restrict__ Bg,
    const unsigned short* __restrict__ Bi, int M, int N, int K,
    unsigned short* __restrict__ outH) {
  __shared__ __align__(16) unsigned short As[2][128 * 64];
  __shared__ __align__(16) unsigned short Gs[2][64 * 64];
  __shared__ __align__(16) unsigned short Is[2][64 * 64];
  const int tid = threadIdx.x;
  const int bm = blockIdx.y * 128, bn = blockIdx.x * 64;
  const int wave = tid >> 6, lane = tid & 63;
  const bool producer = wave >= 4;
  const int pw = wave & 3;
  const int wy = (wave & 3) >> 1, wx = wave & 1;
  const int l15 = lane & 15, quad = lane >> 4;

  const unsigned short* Ab = A + (size_t)bm * K;
  const unsigned short* Gb = Bg + (size_t)bn * K;
  const unsigned short* Ib = Bi + (size_t)bn * K;

  floatx4 accg[4][2], acci[4][2];
  #pragma unroll
  for (int i = 0; i < 4; i++)
    #pragma unroll
    for (int j = 0; j < 2; j++)
      #pragma unroll
      for (int r = 0; r < 4; r++) { accg[i][j][r] = 0.f; acci[i][j][r] = 0.f; }

  int arow[4], brow[2];
  #pragma unroll
  for (int i = 0; i < 4; i++) arow[i] = wy * 64 + i * 16 + l15;
  #pragma unroll
  for (int j = 0; j < 2; j++) brow[j] = wx * 32 + j * 16 + l15;

  const int iters = K >> 6;
  if (producer) {
    stage_rows<128>(Ab, K, As[0], 0, pw, lane);
    stage_rows<64>(Gb, K, Gs[0], 0, pw, lane);
    stage_rows<64>(Ib, K, Is[0], 0, pw, lane);
  }
  __syncthreads();
  for (int it = 0; it < iters; ++it) {
    const int cur = it & 1;
    if (producer) {
      if (it + 1 < iters) {
        stage_rows<128>(Ab, K, As[cur ^ 1], (it + 1) << 6, pw, lane);
        stage_rows<64>(Gb, K, Gs[cur ^ 1], (it + 1) << 6, pw, lane);
        stage_rows<64>(Ib, K, Is[cur ^ 1], (it + 1) << 6, pw, lane);
      }
    } else {
      #pragma unroll
      for (int h = 0; h < 2; h++) {
        bf16x8 afr[4], gfr[2], ifr[2];
        #pragma unroll
        for (int i = 0; i < 4; i++)
          afr[i] = *(const bf16x8*)&As[cur][frag_off64(arow[i], h * 4 + quad)];
        #pragma unroll
        for (int j = 0; j < 2; j++) {
          gfr[j] = *(const bf16x8*)&Gs[cur][frag_off64(brow[j], h * 4 + quad)];
          ifr[j] = *(const bf16x8*)&Is[cur][frag_off64(brow[j], h * 4 + quad)];
        }
        #pragma unroll
        for (int i = 0; i < 4; i++)
          #pragma unroll
          for (int j = 0; j < 2; j++) {
            accg[i][j] = __builtin_amdgcn_mfma_f32_16x16x32_bf16(afr[i], gfr[j], accg[i][j], 0, 0, 0);
            acci[i][j] = __builtin_amdgcn_mfma_f32_16x16x32_bf16(afr[i], ifr[j], acci[i][j], 0, 0, 0);
          }
      }
    }
    __syncthreads();
  }

  if (producer) return;
  #pragma unroll
  for (int i = 0; i < 4; i++)
    #pragma unroll
    for (int j = 0; j < 2; j++) {
      int gm = bm + wy * 64 + i * 16 + quad * 4;
      int gn = bn + wx * 32 + j * 16 + l15;
      #pragma unroll
      for (int r = 0; r < 4; r++) {
        size_t idx = (size_t)(gm + r) * N + gn;
        outH[idx] = f2bf(silu_f(accg[i][j][r]) * acci[i][j][r]);
      }
    }
}

// ------- fused depthwise causal conv (K=5) + residual + rmsnorm -------
// outputs x2 = h + conv(h) and x2n = rmsnorm(x2). Vectorized LDS taps.
#define HS_LD 1040  // skewed row stride (elems): 2080 B -> rows shift 8 banks
__global__ __launch_bounds__(256) void conv_rms_kernel(const unsigned short* __restrict__ h,
                                                       const float* __restrict__ cw,
                                                       unsigned short* __restrict__ x2,
                                                       unsigned short* __restrict__ x2n) {
  int patch = blockIdx.x;  // 0..2047
  __shared__ __align__(16) unsigned short hs[16 * HS_LD];
  __shared__ __align__(16) float cwp[5 * 1024];  // [k][c] planes
  const int tid = threadIdx.x;
  size_t base = (size_t)patch * 16384;
  for (int idx = tid * 8; idx < 16384; idx += 256 * 8) {
    int row = idx >> 10, col = idx & 1023;
    *(uint4*)&hs[row * HS_LD + col] = *(const uint4*)&h[base + idx];
  }
  for (int i = tid; i < 5120; i += 256) {
    int c = i / 5, k = i - c * 5;
    cwp[k * 1024 + c] = cw[i];
  }
  __syncthreads();
  int t = tid >> 4;
  int lc = (tid & 15) * 8;
  float vals[8][8];
  float ss = 0.f;
  #pragma unroll
  for (int jb = 0; jb < 8; jb++) {
    int c = jb * 128 + lc;
    float tap[5][8];
    #pragma unroll
    for (int k = 0; k < 5; k++) {
      int tt = t + k - 4;
      if (tt >= 0) {
        uint4 v = *(const uint4*)&hs[tt * HS_LD + c];
        const unsigned short* vp = (const unsigned short*)&v;
        #pragma unroll
        for (int i = 0; i < 8; i++) tap[k][i] = bf2f(vp[i]);
      } else {
        #pragma unroll
        for (int i = 0; i < 8; i++) tap[k][i] = 0.f;
      }
    }
    float w[5][8];
    #pragma unroll
    for (int k = 0; k < 5; k++) {
      float4 a = *(const float4*)&cwp[k * 1024 + c];
      float4 b = *(const float4*)&cwp[k * 1024 + c + 4];
      w[k][0] = a.x; w[k][1] = a.y; w[k][2] = a.z; w[k][3] = a.w;
      w[k][4] = b.x; w[k][5] = b.y; w[k][6] = b.z; w[k][7] = b.w;
    }
    #pragma unroll
    for (int i = 0; i < 8; i++) {
      float acc = tap[4][i];  // residual (tap k=4 is row t itself)
      #pragma unroll
      for (int k = 0; k < 5; k++) acc += w[k][i] * tap[k][i];
      vals[jb][i] = acc;
      ss += acc * acc;
    }
  }
  ss += __shfl_down(ss, 8, 16);
  ss += __shfl_down(ss, 4, 16);
  ss += __shfl_down(ss, 2, 16);
  ss += __shfl_down(ss, 1, 16);
  ss = __shfl(ss, 0, 16);
  float sc = rsqrtf(ss * (1.f / 1024.f) + 1.1920929e-7f);
  #pragma unroll
  for (int jb = 0; jb < 8; jb++) {
    ushort4 o2[2], on[2];
    #pragma unroll
    for (int i = 0; i < 8; i++) {
      ((unsigned short*)o2)[i] = f2bf(vals[jb][i]);
      ((unsigned short*)on)[i] = f2bf(vals[jb][i] * sc);
    }
    size_t off = base + (size_t)t * 1024 + jb * 128 + lc;
    *(uint4*)&x2[off] = *(uint4*)o2;
    *(uint4*)&x2n[off] = *(uint4*)on;
  }
}

// ---------------- per-patch per-head attention (PS=16, HD=256) ----------------
__global__ __launch_bounds__(256) void attn_kernel(const unsigned short* __restrict__ qkv,
                                                   unsigned short* __restrict__ sa) {
  int patch = blockIdx.x;  // 0..2047
  int head = blockIdx.y;   // 0..3
  const int tid = threadIdx.x;
  __shared__ float qs[16][260], ks[16][260], vs[16][260];
  __shared__ float sc[16][16];
  size_t base = (size_t)patch * 16 * 3072 + (size_t)head * 256;
  for (int idx = tid * 8; idx < 16 * 256; idx += 256 * 8) {
    int t = idx >> 8, d = idx & 255;
    size_t roff = base + (size_t)t * 3072 + d;
    uint4 qv = *(const uint4*)&qkv[roff];
    uint4 kv = *(const uint4*)&qkv[roff + 1024];
    uint4 vv = *(const uint4*)&qkv[roff + 2048];
    const unsigned short* qp = (const unsigned short*)&qv;
    const unsigned short* kp = (const unsigned short*)&kv;
    const unsigned short* vp = (const unsigned short*)&vv;
    #pragma unroll
    for (int i = 0; i < 8; i++) {
      qs[t][d + i] = bf2f(qp[i]);
      ks[t][d + i] = bf2f(kp[i]);
      vs[t][d + i] = bf2f(vp[i]);
    }
  }
  __syncthreads();
  {
    int t = tid >> 4, kk = tid & 15;
    float s = 0.f;
    for (int d = 0; d < 256; d += 4) {
      float4 q = *(const float4*)&qs[t][d];
      float4 k = *(const float4*)&ks[kk][d];
      s += q.x * k.x + q.y * k.y + q.z * k.z + q.w * k.w;
    }
    sc[t][kk] = s * 0.0625f;  // HD^-0.5
  }
  __syncthreads();
  if (tid < 16) {
    float m = -1e30f;
    for (int kk = 0; kk < 16; kk++) m = fmaxf(m, sc[tid][kk]);
    float p[16], sum = 0.f;
    for (int kk = 0; kk < 16; kk++) { p[kk] = __expf(sc[tid][kk] - m); sum += p[kk]; }
    float inv = 1.f / sum;
    for (int kk = 0; kk < 16; kk++) sc[tid][kk] = p[kk] * inv;
  }
  __syncthreads();
  for (int idx = tid * 8; idx < 4096; idx += 256 * 8) {
    int t = idx >> 8, d = idx & 255;
    float o[8] = {0, 0, 0, 0, 0, 0, 0, 0};
    #pragma unroll
    for (int kk = 0; kk < 16; kk++) {
      float w = sc[t][kk];
      float4 v0 = *(const float4*)&vs[kk][d];
      float4 v1 = *(const float4*)&vs[kk][d + 4];
      o[0] += w * v0.x; o[1] += w * v0.y; o[2] += w * v0.z; o[3] += w * v0.w;
      o[4] += w * v1.x; o[5] += w * v1.y; o[6] += w * v1.z; o[7] += w * v1.w;
    }
    ushort4 ov[2];
    #pragma unroll
    for (int i = 0; i < 8; i++) ((unsigned short*)ov)[i] = f2bf(o[i]);
    *(uint4*)&sa[(size_t)(patch * 16 + t) * 1024 + head * 256 + d] = *(uint4*)ov;
  }
}

// -- head pooling with FUSED rmsnorm(x3) input + fused rmsnorm(pooled) out --
// reads x3 (pre-norm); computes per-row rms in-block; logits/pool use
// normalized values; writes pooled (fp32) and pooledn = rmsnorm(pooled) bf16.
__global__ __launch_bounds__(256) void pool_kernel(const unsigned short* __restrict__ x3,
                                                   const float* __restrict__ wpool,
                                                   const float* __restrict__ tptr,
                                                   float* __restrict__ pooled,
                                                   unsigned short* __restrict__ pooledn) {
  int patch = blockIdx.x;  // 0..2047
  __shared__ __align__(16) unsigned short xs[16 * 1024];
  __shared__ float lg[4][16], aw[4][16], srow[16];
  const int tid = threadIdx.x;
  size_t base = (size_t)patch * 16384;
  for (int idx = tid * 8; idx < 16384; idx += 256 * 8)
    *(uint4*)&xs[idx] = *(const uint4*)&x3[base + idx];
  __syncthreads();
  {  // per-row sum of squares: row t = tid>>4, 64 elems per lane
    int t = tid >> 4, sub = tid & 15;
    float ss = 0.f;
    for (int d = sub * 64; d < sub * 64 + 64; d += 4) {
      uint2 v = *(const uint2*)&xs[t * 1024 + d];
      const unsigned short* vp = (const unsigned short*)&v;
      #pragma unroll
      for (int i = 0; i < 4; i++) { float x = bf2f(vp[i]); ss += x * x; }
    }
    ss += __shfl_down(ss, 8, 16);
    ss += __shfl_down(ss, 4, 16);
    ss += __shfl_down(ss, 2, 16);
    ss += __shfl_down(ss, 1, 16);
    if (sub == 0) srow[t] = rsqrtf(ss * (1.f / 1024.f) + 1.1920929e-7f);
  }
  __syncthreads();
  {
    int pair = tid >> 2, sub = tid & 3;
    int t = pair >> 2, hh = pair & 3;
    float s = 0.f;
    for (int d = sub * 256; d < sub * 256 + 256; d++)
      s += bf2f(xs[t * 1024 + d]) * wpool[hh * 1024 + d];
    s += __shfl_down(s, 2, 64);
    s += __shfl_down(s, 1, 64);
    if (sub == 0) {
      float temp = fmaxf(tptr[0], 0.01f);
      lg[hh][t] = s * srow[t] / temp;
    }
  }
  __syncthreads();
  if (tid < 4) {
    int hh = tid;
    float m = -1e30f;
    for (int t = 0; t < 16; t++) m = fmaxf(m, lg[hh][t]);
    float p[16], sum = 0.f;
    for (int t = 0; t < 16; t++) { p[t] = __expf(lg[hh][t] - m); sum += p[t]; }
    float inv = 1.f / sum;
    for (int t = 0; t < 16; t++) aw[hh][t] = p[t] * inv;
  }
  __syncthreads();
  float ov[4]; int cs[4];
  float ss = 0.f;
  #pragma unroll
  for (int q = 0; q < 4; q++) {
    int c = tid + q * 256;
    int hh = c >> 8;
    float o = 0.f;
    #pragma unroll
    for (int t = 0; t < 16; t++) o += aw[hh][t] * srow[t] * bf2f(xs[t * 1024 + c]);
    ov[q] = o; cs[q] = c;
    ss += o * o;
  }
  ss = block_reduce_sum(ss);
  float scn = rsqrtf(ss * (1.f / 1024.f) + 1.1920929e-7f);
  #pragma unroll
  for (int q = 0; q < 4; q++) {
    pooled[(size_t)patch * 1024 + cs[q]] = ov[q];
    pooledn[(size_t)patch * 1024 + cs[q]] = f2bf(ov[q] * scn);
  }
}

extern "C" void kernel_launch(void* const* d_in, const int* in_sizes, int n_in,
                              void* d_out, int out_size, void* d_ws, size_t ws_size,
                              hipStream_t stream) {
  (void)in_sizes; (void)n_in; (void)out_size; (void)ws_size;
  const float* pbe  = (const float*)d_in[0];   // (4,512,16,1024)
  const float* lpos = (const float*)d_in[1];   // (16,1024)
  const float* wg   = (const float*)d_in[2];
  const float* wi   = (const float*)d_in[3];
  const float* cw   = (const float*)d_in[4];   // (1024,1,5)
  const float* wqkv = (const float*)d_in[5];   // (3072,1024)
  const float* wio  = (const float*)d_in[6];
  const float* wpl  = (const float*)d_in[7];   // (4,1024)
  const float* temp = (const float*)d_in[8];
  const float* wup  = (const float*)d_in[9];
  const float* wdn  = (const float*)d_in[10];
  const float* wout = (const float*)d_in[11];
  float* outp = (float*)d_out;                 // (4,512,1024) fp32

  const int ROWS = 32768, Dm = 1024, NPAT = 2048;

  char* p = (char*)d_ws;
  auto take = [&](size_t nbytes) { void* r = (void*)p; p += (nbytes + 255) & ~(size_t)255; return r; };
  unsigned short* wg_b   = (unsigned short*)take((size_t)Dm * Dm * 2);
  unsigned short* wi_b   = (unsigned short*)take((size_t)Dm * Dm * 2);
  unsigned short* wqkv_b = (unsigned short*)take((size_t)3 * Dm * Dm * 2);
  unsigned short* wio_b  = (unsigned short*)take((size_t)Dm * Dm * 2);
  unsigned short* wup_b  = (unsigned short*)take((size_t)Dm * Dm * 2);
  unsigned short* wdn_b  = (unsigned short*)take((size_t)Dm * Dm * 2);
  unsigned short* wout_b = (unsigned short*)take((size_t)Dm * Dm * 2);
  unsigned short* slotA  = (unsigned short*)take((size_t)ROWS * Dm * 2);  // xn / x2n
  unsigned short* slotB  = (unsigned short*)take((size_t)ROWS * Dm * 2);  // h / sa
  unsigned short* slotC  = (unsigned short*)take((size_t)ROWS * Dm * 2);  // x2 / x3
  unsigned short* qkvB   = (unsigned short*)take((size_t)ROWS * 3 * Dm * 2);
  float*          pooled = (float*)take((size_t)NPAT * Dm * 4);
  unsigned short* pooledn= (unsigned short*)take((size_t)NPAT * Dm * 2);
  unsigned short* ubuf   = (unsigned short*)take((size_t)NPAT * Dm * 2);
  unsigned short* y1b    = (unsigned short*)take((size_t)NPAT * Dm * 2);
  float*          y2     = (float*)take((size_t)NPAT * Dm * 4);

  // 0. all weight conversions in one launch
  CvtArgs ca;
  ca.src[0] = wg;   ca.dst[0] = wg_b;
  ca.src[1] = wi;   ca.dst[1] = wi_b;
  ca.src[2] = wqkv; ca.dst[2] = wqkv_b;
  ca.src[3] = wio;  ca.dst[3] = wio_b;
  ca.src[4] = wup;  ca.dst[4] = wup_b;
  ca.src[5] = wdn;  ca.dst[5] = wdn_b;
  ca.src[6] = wout; ca.dst[6] = wout_b;
  int off = 0;
  for (int i = 0; i < 7; i++) { ca.blkoff[i] = off; off += (i == 2) ? 3072 : 1024; }
  ca.blkoff[7] = off;
  cvt_all<<<dim3(off), dim3(256), 0, stream>>>(ca);

  // 1. xn = rmsnorm(pbe + pos)
  prep_kernel<<<dim3(ROWS), dim3(256), 0, stream>>>(pbe, lpos, slotA);
  // 2. h = silu(xn@wg^T) * (xn@wi^T)
  gemm_dual_ws<<<dim3(Dm / 64, ROWS / 128), dim3(512), 0, stream>>>(
      slotA, wg_b, wi_b, ROWS, Dm, Dm, slotB);
  // 3+4. x2 = h + conv(h); x2n = rmsnorm(x2)
  conv_rms_kernel<<<dim3(NPAT), dim3(256), 0, stream>>>(slotB, cw, slotC, slotA);
  // 5. qkv = x2n @ wqkv^T
  gemm_ws<1, 128, 128><<<dim3(3 * Dm / 128, ROWS / 128), dim3(512), 0, stream>>>(
      slotA, wqkv_b, ROWS, 3 * Dm, Dm, nullptr, qkvB, nullptr, nullptr);
  // 6. sa = attention(qkv)
  attn_kernel<<<dim3(NPAT, 4), dim3(256), 0, stream>>>(qkvB, slotB);
  // 7. x3 = x2 + sa @ wio^T   (in-place into slotC)
  gemm_ws<3, 128, 128><<<dim3(Dm / 128, ROWS / 128), dim3(512), 0, stream>>>(
      slotB, wio_b, ROWS, Dm, Dm, nullptr, slotC, slotC, nullptr);
  // 8+9+10. pooled = softmax-pool(rmsnorm(x3)); pooledn = rmsnorm(pooled)
  pool_kernel<<<dim3(NPAT), dim3(256), 0, stream>>>(slotC, wpl, temp, pooled, pooledn);
  // 11. u = silu(pooledn @ wup^T)
  gemm_ws<2, 64, 128><<<dim3(Dm / 128, NPAT / 64), dim3(512), 0, stream>>>(
      pooledn, wup_b, NPAT, Dm, Dm, nullptr, ubuf, nullptr, nullptr);
  // 12. y1 = pooled + u @ wdn^T
  gemm_ws<4, 64, 128><<<dim3(Dm / 128, NPAT / 64), dim3(512), 0, stream>>>(
      ubuf, wdn_b, NPAT, Dm, Dm, nullptr, y1b, nullptr, pooled);
  // 13. y2 = y1 @ wout^T
  gemm_ws<0, 64, 128><<<dim3(Dm / 128, NPAT / 64), dim3(512), 0, stream>>>(
      y1b, wout_b, NPAT, Dm, Dm, y2, nullptr, nullptr, nullptr);
  // 14. out = rmsnorm(y2)
  rmsnorm_kernel<float, float><<<dim3(NPAT), dim3(256), 0, stream>>>(y2, outp);
}